// Round 1
// baseline (92103.119 us; speedup 1.0000x reference)
//
#include <hip/hip_runtime.h>

// ---------------------------------------------------------------------------
// DeepMemoryLevel (ATLAS-style) full f32 implementation.
// B=2 S=1024 D=2048 M=512 P=1024 H=2048 CHUNK=32 NC=32, tokens N=2048.
// Key identity: per-sample grads are rank-1 (outer products), so
// clip_mean(g) == A^T diag(w) B with w_i = 1/(64*max(max(||u_i||*||v_i||,1e-8)/10,1)).
// ---------------------------------------------------------------------------

#define TILE 64
#define KT 16

__device__ __forceinline__ float gelu_f(float x) {
  return 0.5f * x * (1.0f + erff(x * 0.70710678118654752f));
}
__device__ __forceinline__ float gelu_grad_f(float x) {
  float cdf = 0.5f * (1.0f + erff(x * 0.70710678118654752f));
  float pdf = 0.3989422804014327f * expf(-0.5f * x * x);
  return cdf + x * pdf;
}
__device__ __forceinline__ float sigmoid_f(float x) { return 1.0f / (1.0f + expf(-x)); }

__device__ __forceinline__ float block_reduce_sum(float v, float* red) {
  int t = threadIdx.x;
  red[t] = v; __syncthreads();
  for (int s = blockDim.x >> 1; s > 0; s >>= 1) {
    if (t < s) red[t] += red[t + s];
    __syncthreads();
  }
  float r = red[0];
  __syncthreads();
  return r;
}

// ---------------- GEMM ----------------
// C[M,N] = op(A)@op(B), all dims multiples of tile sizes (M,N mult of 64, K of 16).
// TA=0: A=(M,K); TA=1: A=(K,M).  TB=0: B=(K,N); TB=1: B=(N,K).
// AG: chunk-gather rows of A: r -> (r>>5)*1024 + cbase + (r&31)  (M-index if TA==0, K-index if TA==1)
// CS: same map scatters C rows.
// KW: B rows scaled by kw[k].
// EPI: 0 none | 1 gelu | 2 out=c1*acc+c2*emat[m,n] | 3 out=cp[3c+1]*C_old - cp[3c]*acc | 4 out=emat[m,n]+acc*erow[m]
template<int TA, int TB, int EPI, int AG, int CS, int KW>
__global__ __launch_bounds__(256)
void gemm_k(const float* __restrict__ A, const float* __restrict__ B,
            float* __restrict__ C, int M, int N, int K,
            int lda, int ldb, int ldc,
            const float* __restrict__ kw,
            const float* __restrict__ emat, int lde,
            float c1, float c2,
            const float* __restrict__ erow,
            const float* __restrict__ cp, int cidx, int cbase) {
  __shared__ float As[KT][TILE + 4];
  __shared__ float Bs[KT][TILE + 4];
  const int t = threadIdx.x;
  const int tx = t & 15, ty = t >> 4;
  const int n0 = blockIdx.x * TILE, m0 = blockIdx.y * TILE;
  float acc[4][4] = {};

  for (int k0 = 0; k0 < K; k0 += KT) {
    // A tile -> As[kk][mm]
#pragma unroll
    for (int i = 0; i < 4; ++i) {
      int idx = t + i * 256;
      if constexpr (TA == 0) {
        int mm = idx >> 4, kk = idx & 15;
        int row = m0 + mm;
        if constexpr (AG) row = ((row >> 5) << 10) + cbase + (row & 31);
        As[kk][mm] = A[(size_t)row * lda + (k0 + kk)];
      } else {
        int kk = idx >> 6, mm = idx & 63;
        int row = k0 + kk;
        if constexpr (AG) row = ((row >> 5) << 10) + cbase + (row & 31);
        As[kk][mm] = A[(size_t)row * lda + (m0 + mm)];
      }
    }
    // B tile -> Bs[kk][nn]
#pragma unroll
    for (int i = 0; i < 4; ++i) {
      int idx = t + i * 256;
      int kk, nn; float v;
      if constexpr (TB == 0) {
        kk = idx >> 6; nn = idx & 63;
        v = B[(size_t)(k0 + kk) * ldb + (n0 + nn)];
      } else {
        kk = idx & 15; nn = idx >> 4;
        v = B[(size_t)(n0 + nn) * ldb + (k0 + kk)];
      }
      if constexpr (KW) v *= kw[k0 + kk];
      Bs[kk][nn] = v;
    }
    __syncthreads();
#pragma unroll
    for (int kk = 0; kk < KT; ++kk) {
      const float4 av = *(const float4*)&As[kk][ty * 4];
      const float4 bv = *(const float4*)&Bs[kk][tx * 4];
      float aa[4] = {av.x, av.y, av.z, av.w};
      float bb[4] = {bv.x, bv.y, bv.z, bv.w};
#pragma unroll
      for (int i = 0; i < 4; ++i)
#pragma unroll
        for (int j = 0; j < 4; ++j) acc[i][j] += aa[i] * bb[j];
    }
    __syncthreads();
  }

#pragma unroll
  for (int i = 0; i < 4; ++i) {
    int m = m0 + ty * 4 + i;
    int crow = m;
    if constexpr (CS) crow = ((m >> 5) << 10) + cbase + (m & 31);
#pragma unroll
    for (int j = 0; j < 4; ++j) {
      int n = n0 + tx * 4 + j;
      float v = acc[i][j];
      if constexpr (EPI == 1) {
        v = gelu_f(v);
      } else if constexpr (EPI == 2) {
        v = c1 * v + c2 * emat[(size_t)m * lde + n];
      } else if constexpr (EPI == 3) {
        float lr = cp[cidx * 3 + 0], mo = cp[cidx * 3 + 1];
        v = mo * C[(size_t)crow * ldc + n] - lr * v;
      } else if constexpr (EPI == 4) {
        v = emat[(size_t)m * lde + n] + v * erow[m];
      }
      C[(size_t)crow * ldc + n] = v;
    }
  }
}

// ---------------- elementwise / reductions ----------------

// per-token: normalize 512-vec, then poly -> out[n, f]=k/sqrt2, out[n,512+f]=k^2/sqrt2
__global__ __launch_bounds__(256) void polynorm_k(const float* __restrict__ lin,
                                                  float* __restrict__ outp) {
  __shared__ float red[256];
  int n = blockIdx.x, t = threadIdx.x;
  float s = 0.f;
  for (int f = t; f < 512; f += 256) { float v = lin[(size_t)n * 512 + f]; s += v * v; }
  float tot = block_reduce_sum(s, red);
  float sc = 1.0f / fmaxf(sqrtf(tot), 1e-12f);
  const float is2 = 0.70710678118654752f;
  for (int f = t; f < 512; f += 256) {
    float v = lin[(size_t)n * 512 + f] * sc;
    outp[(size_t)n * 1024 + f] = v * is2;
    outp[(size_t)n * 1024 + 512 + f] = v * v * is2;
  }
}

// 4 gates per token
__global__ __launch_bounds__(256) void gates_k(const float* __restrict__ x,
    const float* __restrict__ wlr, const float* __restrict__ blr,
    const float* __restrict__ wmom, const float* __restrict__ bmom,
    const float* __restrict__ wdec, const float* __restrict__ bdec,
    const float* __restrict__ wgate, const float* __restrict__ bgate,
    float* __restrict__ lrv, float* __restrict__ momv,
    float* __restrict__ decv, float* __restrict__ og) {
  __shared__ float red[256];
  int n = blockIdx.x, t = threadIdx.x;
  float s0 = 0.f, s1 = 0.f, s2 = 0.f, s3 = 0.f;
  for (int d = t; d < 2048; d += 256) {
    float xv = x[(size_t)n * 2048 + d];
    s0 += xv * wlr[d]; s1 += xv * wmom[d]; s2 += xv * wdec[d]; s3 += xv * wgate[d];
  }
  float r0 = block_reduce_sum(s0, red);
  float r1 = block_reduce_sum(s1, red);
  float r2 = block_reduce_sum(s2, red);
  float r3 = block_reduce_sum(s3, red);
  if (t == 0) {
    lrv[n] = sigmoid_f(r0 + blr[0]);
    momv[n] = sigmoid_f(r1 + bmom[0]);
    decv[n] = sigmoid_f(r2 + bdec[0]);
    og[n] = sigmoid_f(r3 + bgate[0]);
  }
}

// per-chunk means over 64 tokens -> cp[c*3+{0,1,2}] = {lr, mom, dec}
__global__ void chunk_means_k(const float* __restrict__ lrv, const float* __restrict__ momv,
                              const float* __restrict__ decv, float* __restrict__ cp) {
  int c = blockIdx.x, t = threadIdx.x;  // 64 threads
  int n = ((t >> 5) << 10) + c * 32 + (t & 31);
  float a = lrv[n], b = momv[n], d = decv[n];
  for (int off = 32; off > 0; off >>= 1) {
    a += __shfl_down(a, off);
    b += __shfl_down(b, off);
    d += __shfl_down(d, off);
  }
  if (t == 0) {
    cp[c * 3 + 0] = a * (1.f / 64.f);
    cp[c * 3 + 1] = b * (1.f / 64.f);
    cp[c * 3 + 2] = d * (1.f / 64.f);
  }
}

__global__ __launch_bounds__(256) void gelu_fb_k(const float* __restrict__ h,
                                                 float* __restrict__ a,
                                                 float* __restrict__ gp, int n) {
  for (int i = blockIdx.x * 256 + threadIdx.x; i < n; i += gridDim.x * 256) {
    float v = h[i];
    a[i] = gelu_f(v);
    gp[i] = gelu_grad_f(v);
  }
}

// r = 2*(pred - vexp[chunk rows])   (64 x 1024)
__global__ __launch_bounds__(256) void resid_k(const float* __restrict__ pred,
                                               const float* __restrict__ vexp,
                                               float* __restrict__ r, int cbase) {
  int idx = blockIdx.x * 256 + threadIdx.x;  // 65536 total
  int i = idx >> 10, p = idx & 1023;
  int row = ((i >> 5) << 10) + cbase + (i & 31);
  r[idx] = 2.0f * (pred[idx] - vexp[(size_t)row * 1024 + p]);
}

__global__ __launch_bounds__(256) void mul_k(const float* __restrict__ a,
                                             const float* __restrict__ b,
                                             float* __restrict__ c, int n) {
  for (int i = blockIdx.x * 256 + threadIdx.x; i < n; i += gridDim.x * 256) c[i] = a[i] * b[i];
}

// per-sample clip weights: w = 1/(64*max(max(||u||*||v||,1e-8)/10,1))
__global__ __launch_bounds__(256) void sampnorm_k(const float* __restrict__ kp,
                                                  const float* __restrict__ dh,
                                                  const float* __restrict__ a,
                                                  const float* __restrict__ r,
                                                  float* __restrict__ w0inv,
                                                  float* __restrict__ w1inv, int cbase) {
  __shared__ float red[256];
  int i = blockIdx.x, t = threadIdx.x;
  int row = ((i >> 5) << 10) + cbase + (i & 31);
  float sk = 0.f, sr = 0.f, sdh = 0.f, sa = 0.f;
  for (int p = t; p < 1024; p += 256) {
    float v = kp[(size_t)row * 1024 + p]; sk += v * v;
    v = r[(size_t)i * 1024 + p]; sr += v * v;
  }
  for (int h = t; h < 2048; h += 256) {
    float v = dh[(size_t)i * 2048 + h]; sdh += v * v;
    v = a[(size_t)i * 2048 + h]; sa += v * v;
  }
  float tk = block_reduce_sum(sk, red);
  float tdh = block_reduce_sum(sdh, red);
  float ta = block_reduce_sum(sa, red);
  float tr = block_reduce_sum(sr, red);
  if (t == 0) {
    float n0 = fmaxf(sqrtf(tk) * sqrtf(tdh), 1e-8f);
    float sc0 = fmaxf(n0 * 0.1f, 1.0f);
    w0inv[i] = 1.0f / (64.0f * sc0);
    float n1 = fmaxf(sqrtf(ta) * sqrtf(tr), 1e-8f);
    float sc1 = fmaxf(n1 * 0.1f, 1.0f);
    w1inv[i] = 1.0f / (64.0f * sc1);
  }
}

__global__ __launch_bounds__(256) void frob_k(const float* __restrict__ s, int n,
                                              float* __restrict__ parts) {
  __shared__ float red[256];
  float acc = 0.f;
  for (int i = blockIdx.x * 256 + threadIdx.x; i < n; i += gridDim.x * 256) {
    float v = s[i]; acc += v * v;
  }
  float r = block_reduce_sum(acc, red);
  if (threadIdx.x == 0) parts[blockIdx.x] = r;
}

__global__ __launch_bounds__(256) void frob_fin_k(const float* __restrict__ parts,
                                                  float* __restrict__ inv) {
  __shared__ float red[256];
  float r = block_reduce_sum(parts[threadIdx.x], red);
  if (threadIdx.x == 0) *inv = 1.0f / (sqrtf(r) + 1e-7f);
}

__global__ __launch_bounds__(256) void scale_k(const float* __restrict__ src,
                                               float* __restrict__ dst,
                                               const float* __restrict__ inv, int n) {
  float s = *inv;
  for (int i = blockIdx.x * 256 + threadIdx.x; i < n; i += gridDim.x * 256) dst[i] = src[i] * s;
}

// Xa[p, hh] = S1[hh, p] * inv   (S1: 2048x1024 -> Xa: 1024x2048)
__global__ void tscale_k(const float* __restrict__ S1, float* __restrict__ Xa,
                         const float* __restrict__ inv) {
  __shared__ float tile[32][33];
  float s = *inv;
  int p0 = blockIdx.x * 32, h0 = blockIdx.y * 32;
  int tx = threadIdx.x, ty = threadIdx.y;  // 32 x 8
#pragma unroll
  for (int j = 0; j < 4; ++j)
    tile[ty + 8 * j][tx] = S1[(size_t)(h0 + ty + 8 * j) * 1024 + p0 + tx];
  __syncthreads();
#pragma unroll
  for (int j = 0; j < 4; ++j)
    Xa[(size_t)(p0 + ty + 8 * j) * 2048 + h0 + tx] = tile[tx][ty + 8 * j] * s;
}

// W0 = (1-dec)*W0 + lr*X   elementwise
__global__ __launch_bounds__(256) void wupd_k(float* __restrict__ W, const float* __restrict__ X,
                                              const float* __restrict__ cp, int cidx, int n) {
  float lr = cp[cidx * 3 + 0], dec = cp[cidx * 3 + 2];
  float om = 1.0f - dec;
  for (int i = blockIdx.x * 256 + threadIdx.x; i < n; i += gridDim.x * 256)
    W[i] = om * W[i] + lr * X[i];
}

// W1[hh,p] = (1-dec)*W1[hh,p] + lr*X[p,hh]   (X: 1024x2048, W1: 2048x1024)
__global__ void wupd_t_k(float* __restrict__ W1, const float* __restrict__ X,
                         const float* __restrict__ cp, int cidx) {
  __shared__ float tile[32][33];
  float lr = cp[cidx * 3 + 0], om = 1.0f - cp[cidx * 3 + 2];
  int p0 = blockIdx.x * 32, h0 = blockIdx.y * 32;
  int tx = threadIdx.x, ty = threadIdx.y;  // 32 x 8
#pragma unroll
  for (int j = 0; j < 4; ++j)
    tile[ty + 8 * j][tx] = X[(size_t)(p0 + ty + 8 * j) * 2048 + h0 + tx];
  __syncthreads();
#pragma unroll
  for (int j = 0; j < 4; ++j) {
    size_t idx = (size_t)(h0 + ty + 8 * j) * 1024 + p0 + tx;
    W1[idx] = om * W1[idx] + lr * tile[tx][ty + 8 * j];
  }
}

// ---------------- host ----------------

template<int TA, int TB, int EPI, int AG = 0, int CS = 0, int KW = 0>
static void gemm(hipStream_t s, const float* A, const float* B, float* C,
                 int M, int N, int K, int lda, int ldb, int ldc,
                 const float* kw = nullptr, const float* emat = nullptr, int lde = 0,
                 float c1 = 0.f, float c2 = 0.f, const float* erow = nullptr,
                 const float* cp = nullptr, int cidx = 0, int cbase = 0) {
  dim3 g(N / TILE, M / TILE), b(256);
  hipLaunchKernelGGL((gemm_k<TA, TB, EPI, AG, CS, KW>), g, b, 0, s,
                     A, B, C, M, N, K, lda, ldb, ldc, kw, emat, lde, c1, c2, erow, cp, cidx, cbase);
}

extern "C" void kernel_launch(void* const* d_in, const int* in_sizes, int n_in,
                              void* d_out, int out_size, void* d_ws, size_t ws_size,
                              hipStream_t stream) {
  const float* x = (const float*)d_in[0];
  const float* Wk = (const float*)d_in[1];
  const float* Wv = (const float*)d_in[2];
  const float* Wq = (const float*)d_in[3];
  const float* Wout = (const float*)d_in[4];
  const float* w_lr = (const float*)d_in[5];
  const float* b_lr = (const float*)d_in[6];
  const float* w_mom = (const float*)d_in[7];
  const float* b_mom = (const float*)d_in[8];
  const float* w_dec = (const float*)d_in[9];
  const float* b_dec = (const float*)d_in[10];
  const float* w_gate = (const float*)d_in[11];
  const float* b_gate = (const float*)d_in[12];
  const float* Wmem0 = (const float*)d_in[13];
  const float* Wmem1 = (const float*)d_in[14];
  const float* Wmemout = (const float*)d_in[15];
  const float* Wvexp = (const float*)d_in[16];
  float* out = (float*)d_out;

  const int BIG = 2097152;   // 1024*2048
  const int MED = 1048576;   // 1024*1024 / 2048*512
  const int SM = 131072;     // 64*2048
  float* ws = (float*)d_ws;
  float* kp    = ws;                 // (2048,1024)
  float* qp    = kp + BIG;
  float* vexp  = qp + BIG;
  float* W0    = vexp + BIG;         // (1024,2048)
  float* W1    = W0 + BIG;           // (2048,1024)
  float* S0    = W1 + BIG;
  float* S1    = S0 + BIG;
  float* Xa    = S1 + BIG;
  float* Xb    = Xa + BIG;
  float* Amat  = Xb + BIG;           // (1024,1024)
  float* Bmat  = Amat + MED;
  float* lin   = Bmat + MED;         // (2048,512) scratch for klin/qlin
  float* vlin  = lin + MED;
  float* retrv = vlin + MED;         // (2048,512) retrieved, token layout
  float* ha    = retrv + MED;        // (64,2048)
  float* hbuf  = ha + SM;
  float* abuf  = hbuf + SM;
  float* gpbuf = abuf + SM;
  float* DAbuf = gpbuf + SM;
  float* dhbuf = DAbuf + SM;
  float* predb = dhbuf + SM;         // (64,1024)  also reused for retrieval mid
  float* rbuf  = predb + 65536;
  float* og    = rbuf + 65536;
  float* lrv   = og + 2048;
  float* momv  = lrv + 2048;
  float* decv  = momv + 2048;
  float* cpb   = decv + 2048;        // 32*3
  float* w0inv = cpb + 128;
  float* w1inv = w0inv + 64;
  float* parts = w1inv + 64;         // 256
  float* inv0  = parts + 256;
  float* inv1  = inv0 + 1;
  (void)n_in; (void)in_sizes; (void)out_size;
  if (ws_size < (size_t)(25043460) * sizeof(float)) return;  // need ~96 MiB

  const float NSa = 3.4445f, NSb = -4.7750f, NSc = 2.0315f;

  // ---- working copies / init ----
  hipMemcpyAsync(W0, Wmem0, (size_t)BIG * 4, hipMemcpyDeviceToDevice, stream);
  hipMemcpyAsync(W1, Wmem1, (size_t)BIG * 4, hipMemcpyDeviceToDevice, stream);
  hipMemsetAsync(S0, 0, (size_t)BIG * 4, stream);
  hipMemsetAsync(S1, 0, (size_t)BIG * 4, stream);

  // ---- projections + poly ----
  gemm<0, 1, 0>(stream, x, Wk, lin, 2048, 512, 2048, 2048, 2048, 512);
  hipLaunchKernelGGL(polynorm_k, dim3(2048), dim3(256), 0, stream, lin, kp);
  gemm<0, 1, 0>(stream, x, Wq, lin, 2048, 512, 2048, 2048, 2048, 512);
  hipLaunchKernelGGL(polynorm_k, dim3(2048), dim3(256), 0, stream, lin, qp);
  gemm<0, 1, 0>(stream, x, Wv, vlin, 2048, 512, 2048, 2048, 2048, 512);
  gemm<0, 0, 0>(stream, vlin, Wvexp, vexp, 2048, 1024, 512, 512, 1024, 1024);

  // ---- gates + chunk means ----
  hipLaunchKernelGGL(gates_k, dim3(2048), dim3(256), 0, stream, x,
                     w_lr, b_lr, w_mom, b_mom, w_dec, b_dec, w_gate, b_gate,
                     lrv, momv, decv, og);
  hipLaunchKernelGGL(chunk_means_k, dim3(32), dim3(64), 0, stream, lrv, momv, decv, cpb);

  // ---- sequential chunk scan ----
  for (int c = 0; c < 32; ++c) {
    const int cbase = c * 32;
    // retrieval with pre-update params: gelu(qc@W0)@W1@Wmemout -> retrv (scatter)
    gemm<0, 0, 1, 1>(stream, qp, W0, ha, 64, 2048, 1024, 1024, 2048, 2048,
                     nullptr, nullptr, 0, 0.f, 0.f, nullptr, nullptr, 0, cbase);
    gemm<0, 0, 0>(stream, ha, W1, predb, 64, 1024, 2048, 2048, 1024, 1024);
    gemm<0, 0, 0, 0, 1>(stream, predb, Wmemout, retrv, 64, 512, 1024, 1024, 512, 512,
                        nullptr, nullptr, 0, 0.f, 0.f, nullptr, nullptr, 0, cbase);
    // grads: forward on kc
    gemm<0, 0, 0, 1>(stream, kp, W0, hbuf, 64, 2048, 1024, 1024, 2048, 2048,
                     nullptr, nullptr, 0, 0.f, 0.f, nullptr, nullptr, 0, cbase);
    hipLaunchKernelGGL(gelu_fb_k, dim3(512), dim3(256), 0, stream, hbuf, abuf, gpbuf, SM);
    gemm<0, 0, 0>(stream, abuf, W1, predb, 64, 1024, 2048, 2048, 1024, 1024);
    hipLaunchKernelGGL(resid_k, dim3(256), dim3(256), 0, stream, predb, vexp, rbuf, cbase);
    gemm<0, 1, 0>(stream, rbuf, W1, DAbuf, 64, 2048, 1024, 1024, 1024, 2048);
    hipLaunchKernelGGL(mul_k, dim3(512), dim3(256), 0, stream, DAbuf, gpbuf, dhbuf, SM);
    hipLaunchKernelGGL(sampnorm_k, dim3(64), dim3(256), 0, stream, kp, dhbuf, abuf, rbuf,
                       w0inv, w1inv, cbase);
    // S0 = mom*S0 - lr*(kc^T diag(w0) dh)    S1 = mom*S1 - lr*(a^T diag(w1) r)
    gemm<1, 0, 3, 1, 0, 1>(stream, kp, dhbuf, S0, 1024, 2048, 64, 1024, 2048, 2048,
                           w0inv, nullptr, 0, 0.f, 0.f, nullptr, cpb, c, cbase);
    gemm<1, 0, 3, 0, 0, 1>(stream, abuf, rbuf, S1, 2048, 1024, 64, 2048, 1024, 1024,
                           w1inv, nullptr, 0, 0.f, 0.f, nullptr, cpb, c, 0);

    // ---- NS5 on S0 (1024x2048) ----
    hipLaunchKernelGGL(frob_k, dim3(256), dim3(256), 0, stream, S0, BIG, parts);
    hipLaunchKernelGGL(frob_fin_k, dim3(1), dim3(256), 0, stream, parts, inv0);
    hipLaunchKernelGGL(scale_k, dim3(2048), dim3(256), 0, stream, S0, Xa, inv0, BIG);
    {
      float* Xc = Xa; float* Xn = Xb;
      for (int it = 0; it < 5; ++it) {
        gemm<0, 1, 0>(stream, Xc, Xc, Amat, 1024, 1024, 2048, 2048, 2048, 1024);
        gemm<0, 0, 2>(stream, Amat, Amat, Bmat, 1024, 1024, 1024, 1024, 1024, 1024,
                      nullptr, Amat, 1024, NSc, NSb);
        gemm<0, 0, 2>(stream, Bmat, Xc, Xn, 1024, 2048, 1024, 1024, 2048, 2048,
                      nullptr, Xc, 2048, 1.0f, NSa);
        float* tmp = Xc; Xc = Xn; Xn = tmp;
      }
      hipLaunchKernelGGL(wupd_k, dim3(2048), dim3(256), 0, stream, W0, Xc, cpb, c, BIG);
    }
    // ---- NS5 on S1^T (run loop on 1024x2048, write back transposed) ----
    hipLaunchKernelGGL(frob_k, dim3(256), dim3(256), 0, stream, S1, BIG, parts);
    hipLaunchKernelGGL(frob_fin_k, dim3(1), dim3(256), 0, stream, parts, inv1);
    hipLaunchKernelGGL(tscale_k, dim3(32, 64), dim3(32, 8), 0, stream, S1, Xa, inv1);
    {
      float* Xc = Xa; float* Xn = Xb;
      for (int it = 0; it < 5; ++it) {
        gemm<0, 1, 0>(stream, Xc, Xc, Amat, 1024, 1024, 2048, 2048, 2048, 1024);
        gemm<0, 0, 2>(stream, Amat, Amat, Bmat, 1024, 1024, 1024, 1024, 1024, 1024,
                      nullptr, Amat, 1024, NSc, NSb);
        gemm<0, 0, 2>(stream, Bmat, Xc, Xn, 1024, 2048, 1024, 1024, 2048, 2048,
                      nullptr, Xc, 2048, 1.0f, NSa);
        float* tmp = Xc; Xc = Xn; Xn = tmp;
      }
      hipLaunchKernelGGL(wupd_t_k, dim3(32, 64), dim3(32, 8), 0, stream, W1, Xc, cpb, c);
    }
  }

  // ---- final: out = x + (retrieved @ Wout^T) * og ----
  gemm<0, 1, 4>(stream, retrv, Wout, out, 2048, 2048, 512, 512, 512, 2048,
                nullptr, x, 2048, 0.f, 0.f, og);
}

// Round 3
// 32432.291 us; speedup vs baseline: 2.8399x; 2.8399x over previous
//
#include <hip/hip_runtime.h>

// ---------------------------------------------------------------------------
// DeepMemoryLevel (ATLAS-style). B=2 S=1024 D=2048 M=512 P=1024 H=2048
// CHUNK=32 NC=32, tokens N=2048.
// Round 2 (resubmit after infra failure): NS5 orthogonalization on bf16 MFMA
// (16x16x32), batched over the two matrices (S0-chain, S1^T-chain) via
// grid.z=2. Everything else f32.
// ---------------------------------------------------------------------------

#define TILE 64
#define KT 16

typedef __attribute__((ext_vector_type(8))) short s16x8;
typedef __attribute__((ext_vector_type(8))) unsigned short u16x8;
typedef __attribute__((ext_vector_type(4))) float f32x4;

__device__ __forceinline__ float gelu_f(float x) {
  return 0.5f * x * (1.0f + erff(x * 0.70710678118654752f));
}
__device__ __forceinline__ float gelu_grad_f(float x) {
  float cdf = 0.5f * (1.0f + erff(x * 0.70710678118654752f));
  float pdf = 0.3989422804014327f * expf(-0.5f * x * x);
  return cdf + x * pdf;
}
__device__ __forceinline__ float sigmoid_f(float x) { return 1.0f / (1.0f + expf(-x)); }

__device__ __forceinline__ unsigned short f2bf(float f) {
  union { float f; unsigned u; } v; v.f = f;
  unsigned r = (v.u + 0x7FFFu + ((v.u >> 16) & 1u)) >> 16;
  return (unsigned short)r;
}
__device__ __forceinline__ float bf2f(unsigned short h) {
  union { unsigned u; float f; } v; v.u = ((unsigned)h) << 16;
  return v.f;
}

__device__ __forceinline__ float block_reduce_sum(float v, float* red) {
  int t = threadIdx.x;
  red[t] = v; __syncthreads();
  for (int s = blockDim.x >> 1; s > 0; s >>= 1) {
    if (t < s) red[t] += red[t + s];
    __syncthreads();
  }
  float r = red[0];
  __syncthreads();
  return r;
}

// ---------------- bf16 MFMA GEMM (batched, TB=1 only) ----------------
// C[M,N] = A @ B^T_rowmajorNK + epilogue.  A: bf16 row-major M x K (lda).
// B: bf16 row-major N x K (ldb)  (i.e. math-B[k][n] = Bsrc[n][k]).
// EPI 5: C(bf16) = acc.   EPI 6: C(bf16) = c1*acc + c2*bf(E[m,n]).
// M,N multiples of 128; K multiple of 64. grid.z = batch, strides in elems.
#define MBM 128
#define MBN 128
#define MBK 64
#define MKP 72

template<int EPI>
__global__ __launch_bounds__(256)
void mgemm_k(const unsigned short* __restrict__ Aq, const unsigned short* __restrict__ Bq,
             unsigned short* __restrict__ Cq, const unsigned short* __restrict__ Eq,
             int M, int N, int K, int lda, int ldb, int ldc, int lde,
             float c1, float c2, long sA, long sB, long sC, long sE) {
  __shared__ __align__(16) unsigned short As[MBM * MKP];
  __shared__ __align__(16) unsigned short Bs[MBN * MKP];
  const int bz = blockIdx.z;
  const unsigned short* A = Aq + (size_t)bz * sA;
  const unsigned short* B = Bq + (size_t)bz * sB;
  const unsigned short* E = Eq + (size_t)bz * sE;
  unsigned short* C = Cq + (size_t)bz * sC;
  const int t = threadIdx.x;
  const int m0 = blockIdx.y * MBM, n0 = blockIdx.x * MBN;
  const int wave = t >> 6, lane = t & 63;
  const int wm = (wave >> 1) * 64, wn = (wave & 1) * 64;
  const int l15 = lane & 15, l4 = lane >> 4;

  f32x4 acc[4][4];
#pragma unroll
  for (int i = 0; i < 4; ++i)
#pragma unroll
    for (int j = 0; j < 4; ++j) acc[i][j] = (f32x4){0.f, 0.f, 0.f, 0.f};

  const int sm = t >> 1;            // staging row 0..127
  const int sk = (t & 1) * 32;      // staging k offset

  for (int k0 = 0; k0 < K; k0 += MBK) {
    {
      const unsigned short* src = A + (size_t)(m0 + sm) * lda + k0 + sk;
      u16x8 v0 = *(const u16x8*)(src);
      u16x8 v1 = *(const u16x8*)(src + 8);
      u16x8 v2 = *(const u16x8*)(src + 16);
      u16x8 v3 = *(const u16x8*)(src + 24);
      unsigned short* dst = &As[sm * MKP + sk];
      *(u16x8*)(dst) = v0; *(u16x8*)(dst + 8) = v1;
      *(u16x8*)(dst + 16) = v2; *(u16x8*)(dst + 24) = v3;
    }
    {
      const unsigned short* src = B + (size_t)(n0 + sm) * ldb + k0 + sk;
      u16x8 v0 = *(const u16x8*)(src);
      u16x8 v1 = *(const u16x8*)(src + 8);
      u16x8 v2 = *(const u16x8*)(src + 16);
      u16x8 v3 = *(const u16x8*)(src + 24);
      unsigned short* dst = &Bs[sm * MKP + sk];
      *(u16x8*)(dst) = v0; *(u16x8*)(dst + 8) = v1;
      *(u16x8*)(dst + 16) = v2; *(u16x8*)(dst + 24) = v3;
    }
    __syncthreads();
#pragma unroll
    for (int ks = 0; ks < 2; ++ks) {
      s16x8 af[4], bfr[4];
#pragma unroll
      for (int mi = 0; mi < 4; ++mi)
        af[mi] = *(const s16x8*)&As[(wm + mi * 16 + l15) * MKP + ks * 32 + l4 * 8];
#pragma unroll
      for (int ni = 0; ni < 4; ++ni)
        bfr[ni] = *(const s16x8*)&Bs[(wn + ni * 16 + l15) * MKP + ks * 32 + l4 * 8];
#pragma unroll
      for (int mi = 0; mi < 4; ++mi)
#pragma unroll
        for (int ni = 0; ni < 4; ++ni)
          acc[mi][ni] = __builtin_amdgcn_mfma_f32_16x16x32_bf16(af[mi], bfr[ni], acc[mi][ni], 0, 0, 0);
    }
    __syncthreads();
  }

#pragma unroll
  for (int mi = 0; mi < 4; ++mi) {
#pragma unroll
    for (int i = 0; i < 4; ++i) {
      int row = m0 + wm + mi * 16 + l4 * 4 + i;
#pragma unroll
      for (int ni = 0; ni < 4; ++ni) {
        int col = n0 + wn + ni * 16 + l15;
        float v = acc[mi][ni][i];
        if constexpr (EPI == 6) v = c1 * v + c2 * bf2f(E[(size_t)row * lde + col]);
        C[(size_t)row * ldc + col] = f2bf(v);
      }
    }
  }
}

template<int EPI>
static void mgemm(hipStream_t s, const unsigned short* A, const unsigned short* B,
                  unsigned short* C, const unsigned short* E,
                  int M, int N, int K, int lda, int ldb, int ldc, int lde,
                  float c1, float c2, long sA, long sB, long sC, long sE, int batch) {
  dim3 g(N / MBN, M / MBM, batch), b(256);
  hipLaunchKernelGGL((mgemm_k<EPI>), g, b, 0, s, A, B, C, E, M, N, K,
                     lda, ldb, ldc, lde, c1, c2, sA, sB, sC, sE);
}

// ---------------- f32 GEMM (vector ALU) ----------------
// C[M,N] = op(A)@op(B). TA=0: A=(M,K); TA=1: A=(K,M). TB=0: B=(K,N); TB=1: B=(N,K).
// AG: chunk-gather rows of A; CS: scatter C rows; KW: B rows scaled by kw[k].
// EPI: 0 none | 1 gelu | 3 out=cp[3c+1]*C_old - cp[3c]*acc | 4 out=emat[m,n]+acc*erow[m]
template<int TA, int TB, int EPI, int AG, int CS, int KW>
__global__ __launch_bounds__(256)
void gemm_k(const float* __restrict__ A, const float* __restrict__ B,
            float* __restrict__ C, int M, int N, int K,
            int lda, int ldb, int ldc,
            const float* __restrict__ kw,
            const float* __restrict__ emat, int lde,
            float c1, float c2,
            const float* __restrict__ erow,
            const float* __restrict__ cp, int cidx, int cbase) {
  __shared__ float As[KT][TILE + 4];
  __shared__ float Bs[KT][TILE + 4];
  const int t = threadIdx.x;
  const int tx = t & 15, ty = t >> 4;
  const int n0 = blockIdx.x * TILE, m0 = blockIdx.y * TILE;
  float acc[4][4] = {};

  for (int k0 = 0; k0 < K; k0 += KT) {
#pragma unroll
    for (int i = 0; i < 4; ++i) {
      int idx = t + i * 256;
      if constexpr (TA == 0) {
        int mm = idx >> 4, kk = idx & 15;
        int row = m0 + mm;
        if constexpr (AG) row = ((row >> 5) << 10) + cbase + (row & 31);
        As[kk][mm] = A[(size_t)row * lda + (k0 + kk)];
      } else {
        int kk = idx >> 6, mm = idx & 63;
        int row = k0 + kk;
        if constexpr (AG) row = ((row >> 5) << 10) + cbase + (row & 31);
        As[kk][mm] = A[(size_t)row * lda + (m0 + mm)];
      }
    }
#pragma unroll
    for (int i = 0; i < 4; ++i) {
      int idx = t + i * 256;
      int kk, nn; float v;
      if constexpr (TB == 0) {
        kk = idx >> 6; nn = idx & 63;
        v = B[(size_t)(k0 + kk) * ldb + (n0 + nn)];
      } else {
        kk = idx & 15; nn = idx >> 4;
        v = B[(size_t)(n0 + nn) * ldb + (k0 + kk)];
      }
      if constexpr (KW) v *= kw[k0 + kk];
      Bs[kk][nn] = v;
    }
    __syncthreads();
#pragma unroll
    for (int kk = 0; kk < KT; ++kk) {
      const float4 av = *(const float4*)&As[kk][ty * 4];
      const float4 bv = *(const float4*)&Bs[kk][tx * 4];
      float aa[4] = {av.x, av.y, av.z, av.w};
      float bb[4] = {bv.x, bv.y, bv.z, bv.w};
#pragma unroll
      for (int i = 0; i < 4; ++i)
#pragma unroll
        for (int j = 0; j < 4; ++j) acc[i][j] += aa[i] * bb[j];
    }
    __syncthreads();
  }

#pragma unroll
  for (int i = 0; i < 4; ++i) {
    int m = m0 + ty * 4 + i;
    int crow = m;
    if constexpr (CS) crow = ((m >> 5) << 10) + cbase + (m & 31);
#pragma unroll
    for (int j = 0; j < 4; ++j) {
      int n = n0 + tx * 4 + j;
      float v = acc[i][j];
      if constexpr (EPI == 1) {
        v = gelu_f(v);
      } else if constexpr (EPI == 3) {
        float lr = cp[cidx * 3 + 0], mo = cp[cidx * 3 + 1];
        v = mo * C[(size_t)crow * ldc + n] - lr * v;
      } else if constexpr (EPI == 4) {
        v = emat[(size_t)m * lde + n] + v * erow[m];
      }
      C[(size_t)crow * ldc + n] = v;
    }
  }
}

// ---------------- elementwise / reductions ----------------

__global__ __launch_bounds__(256) void polynorm_k(const float* __restrict__ lin,
                                                  float* __restrict__ outp) {
  __shared__ float red[256];
  int n = blockIdx.x, t = threadIdx.x;
  float s = 0.f;
  for (int f = t; f < 512; f += 256) { float v = lin[(size_t)n * 512 + f]; s += v * v; }
  float tot = block_reduce_sum(s, red);
  float sc = 1.0f / fmaxf(sqrtf(tot), 1e-12f);
  const float is2 = 0.70710678118654752f;
  for (int f = t; f < 512; f += 256) {
    float v = lin[(size_t)n * 512 + f] * sc;
    outp[(size_t)n * 1024 + f] = v * is2;
    outp[(size_t)n * 1024 + 512 + f] = v * v * is2;
  }
}

__global__ __launch_bounds__(256) void gates_k(const float* __restrict__ x,
    const float* __restrict__ wlr, const float* __restrict__ blr,
    const float* __restrict__ wmom, const float* __restrict__ bmom,
    const float* __restrict__ wdec, const float* __restrict__ bdec,
    const float* __restrict__ wgate, const float* __restrict__ bgate,
    float* __restrict__ lrv, float* __restrict__ momv,
    float* __restrict__ decv, float* __restrict__ og) {
  __shared__ float red[256];
  int n = blockIdx.x, t = threadIdx.x;
  float s0 = 0.f, s1 = 0.f, s2 = 0.f, s3 = 0.f;
  for (int d = t; d < 2048; d += 256) {
    float xv = x[(size_t)n * 2048 + d];
    s0 += xv * wlr[d]; s1 += xv * wmom[d]; s2 += xv * wdec[d]; s3 += xv * wgate[d];
  }
  float r0 = block_reduce_sum(s0, red);
  float r1 = block_reduce_sum(s1, red);
  float r2 = block_reduce_sum(s2, red);
  float r3 = block_reduce_sum(s3, red);
  if (t == 0) {
    lrv[n] = sigmoid_f(r0 + blr[0]);
    momv[n] = sigmoid_f(r1 + bmom[0]);
    decv[n] = sigmoid_f(r2 + bdec[0]);
    og[n] = sigmoid_f(r3 + bgate[0]);
  }
}

__global__ void chunk_means_k(const float* __restrict__ lrv, const float* __restrict__ momv,
                              const float* __restrict__ decv, float* __restrict__ cp) {
  int c = blockIdx.x, t = threadIdx.x;  // 64 threads
  int n = ((t >> 5) << 10) + c * 32 + (t & 31);
  float a = lrv[n], b = momv[n], d = decv[n];
  for (int off = 32; off > 0; off >>= 1) {
    a += __shfl_down(a, off);
    b += __shfl_down(b, off);
    d += __shfl_down(d, off);
  }
  if (t == 0) {
    cp[c * 3 + 0] = a * (1.f / 64.f);
    cp[c * 3 + 1] = b * (1.f / 64.f);
    cp[c * 3 + 2] = d * (1.f / 64.f);
  }
}

__global__ __launch_bounds__(256) void gelu_fb_k(const float* __restrict__ h,
                                                 float* __restrict__ a,
                                                 float* __restrict__ gp, int n) {
  for (int i = blockIdx.x * 256 + threadIdx.x; i < n; i += gridDim.x * 256) {
    float v = h[i];
    a[i] = gelu_f(v);
    gp[i] = gelu_grad_f(v);
  }
}

__global__ __launch_bounds__(256) void resid_k(const float* __restrict__ pred,
                                               const float* __restrict__ vexp,
                                               float* __restrict__ r, int cbase) {
  int idx = blockIdx.x * 256 + threadIdx.x;  // 65536 total
  int i = idx >> 10, p = idx & 1023;
  int row = ((i >> 5) << 10) + cbase + (i & 31);
  r[idx] = 2.0f * (pred[idx] - vexp[(size_t)row * 1024 + p]);
}

__global__ __launch_bounds__(256) void mul_k(const float* __restrict__ a,
                                             const float* __restrict__ b,
                                             float* __restrict__ c, int n) {
  for (int i = blockIdx.x * 256 + threadIdx.x; i < n; i += gridDim.x * 256) c[i] = a[i] * b[i];
}

__global__ __launch_bounds__(256) void sampnorm_k(const float* __restrict__ kp,
                                                  const float* __restrict__ dh,
                                                  const float* __restrict__ a,
                                                  const float* __restrict__ r,
                                                  float* __restrict__ w0inv,
                                                  float* __restrict__ w1inv, int cbase) {
  __shared__ float red[256];
  int i = blockIdx.x, t = threadIdx.x;
  int row = ((i >> 5) << 10) + cbase + (i & 31);
  float sk = 0.f, sr = 0.f, sdh = 0.f, sa = 0.f;
  for (int p = t; p < 1024; p += 256) {
    float v = kp[(size_t)row * 1024 + p]; sk += v * v;
    v = r[(size_t)i * 1024 + p]; sr += v * v;
  }
  for (int h = t; h < 2048; h += 256) {
    float v = dh[(size_t)i * 2048 + h]; sdh += v * v;
    v = a[(size_t)i * 2048 + h]; sa += v * v;
  }
  float tk = block_reduce_sum(sk, red);
  float tdh = block_reduce_sum(sdh, red);
  float ta = block_reduce_sum(sa, red);
  float tr = block_reduce_sum(sr, red);
  if (t == 0) {
    float n0 = fmaxf(sqrtf(tk) * sqrtf(tdh), 1e-8f);
    w0inv[i] = 1.0f / (64.0f * fmaxf(n0 * 0.1f, 1.0f));
    float n1 = fmaxf(sqrtf(ta) * sqrtf(tr), 1e-8f);
    w1inv[i] = 1.0f / (64.0f * fmaxf(n1 * 0.1f, 1.0f));
  }
}

__global__ __launch_bounds__(256) void frob_k(const float* __restrict__ s, int n,
                                              float* __restrict__ parts) {
  __shared__ float red[256];
  float acc = 0.f;
  for (int i = blockIdx.x * 256 + threadIdx.x; i < n; i += gridDim.x * 256) {
    float v = s[i]; acc += v * v;
  }
  float r = block_reduce_sum(acc, red);
  if (threadIdx.x == 0) parts[blockIdx.x] = r;
}

__global__ __launch_bounds__(256) void frob_fin_k(const float* __restrict__ parts,
                                                  float* __restrict__ inv) {
  __shared__ float red[256];
  float r = block_reduce_sum(parts[threadIdx.x], red);
  if (threadIdx.x == 0) *inv = 1.0f / (sqrtf(r) + 1e-7f);
}

// dst_bf16 = src_f32 * (*inv)
__global__ __launch_bounds__(256) void scalebf_k(const float* __restrict__ src,
                                                 unsigned short* __restrict__ dst,
                                                 const float* __restrict__ inv, int n) {
  float s = *inv;
  for (int i = blockIdx.x * 256 + threadIdx.x; i < n; i += gridDim.x * 256)
    dst[i] = f2bf(src[i] * s);
}

// out_bf16[C x R] = (in_f32[R x C])^T * (*inv)
__global__ void tscalebf_k(const float* __restrict__ in, unsigned short* __restrict__ out,
                           const float* __restrict__ inv, int R, int C) {
  __shared__ float tile[32][33];
  float s = *inv;
  int c0 = blockIdx.x * 32, r0 = blockIdx.y * 32;
  int tx = threadIdx.x, ty = threadIdx.y;
#pragma unroll
  for (int j = 0; j < 4; ++j)
    tile[ty + 8 * j][tx] = in[(size_t)(r0 + ty + 8 * j) * C + c0 + tx];
  __syncthreads();
#pragma unroll
  for (int j = 0; j < 4; ++j)
    out[(size_t)(c0 + ty + 8 * j) * R + r0 + tx] = f2bf(tile[tx][ty + 8 * j] * s);
}

// batched bf16 transpose: in[2][1024][2048] -> out[2][2048][1024]
__global__ void tbf_k(const unsigned short* __restrict__ in, unsigned short* __restrict__ out) {
  __shared__ unsigned short tile[32][33];
  size_t bo = (size_t)blockIdx.z * 2097152;
  int c0 = blockIdx.x * 32, r0 = blockIdx.y * 32;
  int tx = threadIdx.x, ty = threadIdx.y;
#pragma unroll
  for (int j = 0; j < 4; ++j)
    tile[ty + 8 * j][tx] = in[bo + (size_t)(r0 + ty + 8 * j) * 2048 + c0 + tx];
  __syncthreads();
#pragma unroll
  for (int j = 0; j < 4; ++j)
    out[bo + (size_t)(c0 + ty + 8 * j) * 1024 + r0 + tx] = tile[tx][ty + 8 * j];
}

// W0 = (1-dec)*W0 + lr*bf(X)
__global__ __launch_bounds__(256) void wupdbf_k(float* __restrict__ W,
                                                const unsigned short* __restrict__ X,
                                                const float* __restrict__ cp, int cidx, int n) {
  float lr = cp[cidx * 3 + 0], om = 1.0f - cp[cidx * 3 + 2];
  for (int i = blockIdx.x * 256 + threadIdx.x; i < n; i += gridDim.x * 256)
    W[i] = om * W[i] + lr * bf2f(X[i]);
}

// W1[h][p] = (1-dec)*W1[h][p] + lr*bf(X[p][h])   (X: 1024x2048 bf16, W1: 2048x1024 f32)
__global__ void wupd_t_bf_k(float* __restrict__ W1, const unsigned short* __restrict__ X,
                            const float* __restrict__ cp, int cidx) {
  __shared__ float tile[32][33];
  float lr = cp[cidx * 3 + 0], om = 1.0f - cp[cidx * 3 + 2];
  int p0 = blockIdx.x * 32, h0 = blockIdx.y * 32;
  int tx = threadIdx.x, ty = threadIdx.y;
#pragma unroll
  for (int j = 0; j < 4; ++j)
    tile[ty + 8 * j][tx] = bf2f(X[(size_t)(p0 + ty + 8 * j) * 2048 + h0 + tx]);
  __syncthreads();
#pragma unroll
  for (int j = 0; j < 4; ++j) {
    size_t idx = (size_t)(h0 + ty + 8 * j) * 1024 + p0 + tx;
    W1[idx] = om * W1[idx] + lr * tile[tx][ty + 8 * j];
  }
}

// ---------------- host ----------------

template<int TA, int TB, int EPI, int AG = 0, int CS = 0, int KW = 0>
static void gemm(hipStream_t s, const float* A, const float* B, float* C,
                 int M, int N, int K, int lda, int ldb, int ldc,
                 const float* kw = nullptr, const float* emat = nullptr, int lde = 0,
                 float c1 = 0.f, float c2 = 0.f, const float* erow = nullptr,
                 const float* cp = nullptr, int cidx = 0, int cbase = 0) {
  dim3 g(N / TILE, M / TILE), b(256);
  hipLaunchKernelGGL((gemm_k<TA, TB, EPI, AG, CS, KW>), g, b, 0, s,
                     A, B, C, M, N, K, lda, ldb, ldc, kw, emat, lde, c1, c2, erow, cp, cidx, cbase);
}

extern "C" void kernel_launch(void* const* d_in, const int* in_sizes, int n_in,
                              void* d_out, int out_size, void* d_ws, size_t ws_size,
                              hipStream_t stream) {
  const float* x = (const float*)d_in[0];
  const float* Wk = (const float*)d_in[1];
  const float* Wv = (const float*)d_in[2];
  const float* Wq = (const float*)d_in[3];
  const float* Wout = (const float*)d_in[4];
  const float* w_lr = (const float*)d_in[5];
  const float* b_lr = (const float*)d_in[6];
  const float* w_mom = (const float*)d_in[7];
  const float* b_mom = (const float*)d_in[8];
  const float* w_dec = (const float*)d_in[9];
  const float* b_dec = (const float*)d_in[10];
  const float* w_gate = (const float*)d_in[11];
  const float* b_gate = (const float*)d_in[12];
  const float* Wmem0 = (const float*)d_in[13];
  const float* Wmem1 = (const float*)d_in[14];
  const float* Wmemout = (const float*)d_in[15];
  const float* Wvexp = (const float*)d_in[16];
  float* out = (float*)d_out;

  const int BIG = 2097152;   // 1024*2048
  const int MED = 1048576;
  const int SM = 131072;     // 64*2048
  const long SB2 = 2097152, SB1 = 1048576;
  float* ws = (float*)d_ws;
  float* kp    = ws;                 // (2048,1024) f32
  float* qp    = kp + BIG;
  float* vexp  = qp + BIG;
  float* W0    = vexp + BIG;         // (1024,2048) f32
  float* W1    = W0 + BIG;           // (2048,1024) f32
  float* S0    = W1 + BIG;
  float* S1    = S0 + BIG;
  float* bfreg = S1 + BIG;           // 6M floats of bf16 buffers
  unsigned short* XA = (unsigned short*)bfreg;   // [2][1024][2048] bf16
  unsigned short* XB = XA + 2 * BIG;             // [2][1024][2048] bf16
  unsigned short* XT = XB + 2 * BIG;             // [2][2048][1024] bf16
  float* lin   = bfreg + 3 * (long)BIG;  // (2048,512) f32 (prologue only)
  float* vlin  = lin + MED;              // (2048,512) f32 (prologue only)
  unsigned short* Ab = (unsigned short*)lin;     // [2][1024][1024] bf16 (loop)
  unsigned short* Bb = (unsigned short*)vlin;    // [2][1024][1024] bf16 (loop)
  float* retrv = vlin + MED;         // (2048,512)
  float* ha    = retrv + MED;        // (64,2048)
  float* hbuf  = ha + SM;
  float* abuf  = hbuf + SM;
  float* gpbuf = abuf + SM;
  float* DAbuf = gpbuf + SM;
  float* dhbuf = DAbuf + SM;
  float* predb = dhbuf + SM;         // (64,1024)
  float* rbuf  = predb + 65536;
  float* og    = rbuf + 65536;
  float* lrv   = og + 2048;
  float* momv  = lrv + 2048;
  float* decv  = momv + 2048;
  float* cpb   = decv + 2048;        // 32*3
  float* w0inv = cpb + 128;
  float* w1inv = w0inv + 64;
  float* parts = w1inv + 64;         // 256
  float* inv0  = parts + 256;
  float* inv1  = inv0 + 1;
  (void)n_in; (void)in_sizes; (void)out_size;
  if (ws_size < (size_t)(25043464) * sizeof(float)) return;

  const float NSa = 3.4445f, NSb = -4.7750f, NSc = 2.0315f;

  hipMemcpyAsync(W0, Wmem0, (size_t)BIG * 4, hipMemcpyDeviceToDevice, stream);
  hipMemcpyAsync(W1, Wmem1, (size_t)BIG * 4, hipMemcpyDeviceToDevice, stream);
  hipMemsetAsync(S0, 0, (size_t)BIG * 4, stream);
  hipMemsetAsync(S1, 0, (size_t)BIG * 4, stream);

  // ---- projections + poly ----
  gemm<0, 1, 0>(stream, x, Wk, lin, 2048, 512, 2048, 2048, 2048, 512);
  hipLaunchKernelGGL(polynorm_k, dim3(2048), dim3(256), 0, stream, lin, kp);
  gemm<0, 1, 0>(stream, x, Wq, lin, 2048, 512, 2048, 2048, 2048, 512);
  hipLaunchKernelGGL(polynorm_k, dim3(2048), dim3(256), 0, stream, lin, qp);
  gemm<0, 1, 0>(stream, x, Wv, vlin, 2048, 512, 2048, 2048, 2048, 512);
  gemm<0, 0, 0>(stream, vlin, Wvexp, vexp, 2048, 1024, 512, 512, 1024, 1024);

  // ---- gates + chunk means ----
  hipLaunchKernelGGL(gates_k, dim3(2048), dim3(256), 0, stream, x,
                     w_lr, b_lr, w_mom, b_mom, w_dec, b_dec, w_gate, b_gate,
                     lrv, momv, decv, og);
  hipLaunchKernelGGL(chunk_means_k, dim3(32), dim3(64), 0, stream, lrv, momv, decv, cpb);

  // ---- sequential chunk scan ----
  for (int c = 0; c < 32; ++c) {
    const int cbase = c * 32;
    // retrieval with pre-update params
    gemm<0, 0, 1, 1>(stream, qp, W0, ha, 64, 2048, 1024, 1024, 2048, 2048,
                     nullptr, nullptr, 0, 0.f, 0.f, nullptr, nullptr, 0, cbase);
    gemm<0, 0, 0>(stream, ha, W1, predb, 64, 1024, 2048, 2048, 1024, 1024);
    gemm<0, 0, 0, 0, 1>(stream, predb, Wmemout, retrv, 64, 512, 1024, 1024, 512, 512,
                        nullptr, nullptr, 0, 0.f, 0.f, nullptr, nullptr, 0, cbase);
    // grads (rank-1 per-sample -> weighted K=64 GEMMs)
    gemm<0, 0, 0, 1>(stream, kp, W0, hbuf, 64, 2048, 1024, 1024, 2048, 2048,
                     nullptr, nullptr, 0, 0.f, 0.f, nullptr, nullptr, 0, cbase);
    hipLaunchKernelGGL(gelu_fb_k, dim3(512), dim3(256), 0, stream, hbuf, abuf, gpbuf, SM);
    gemm<0, 0, 0>(stream, abuf, W1, predb, 64, 1024, 2048, 2048, 1024, 1024);
    hipLaunchKernelGGL(resid_k, dim3(256), dim3(256), 0, stream, predb, vexp, rbuf, cbase);
    gemm<0, 1, 0>(stream, rbuf, W1, DAbuf, 64, 2048, 1024, 1024, 1024, 2048);
    hipLaunchKernelGGL(mul_k, dim3(512), dim3(256), 0, stream, DAbuf, gpbuf, dhbuf, SM);
    hipLaunchKernelGGL(sampnorm_k, dim3(64), dim3(256), 0, stream, kp, dhbuf, abuf, rbuf,
                       w0inv, w1inv, cbase);
    gemm<1, 0, 3, 1, 0, 1>(stream, kp, dhbuf, S0, 1024, 2048, 64, 1024, 2048, 2048,
                           w0inv, nullptr, 0, 0.f, 0.f, nullptr, cpb, c, cbase);
    gemm<1, 0, 3, 0, 0, 1>(stream, abuf, rbuf, S1, 2048, 1024, 64, 2048, 1024, 1024,
                           w1inv, nullptr, 0, 0.f, 0.f, nullptr, cpb, c, 0);

    // ---- batched NS5 (bf16 MFMA): batch0 = S0 (1024x2048), batch1 = S1^T ----
    hipLaunchKernelGGL(frob_k, dim3(256), dim3(256), 0, stream, S0, BIG, parts);
    hipLaunchKernelGGL(frob_fin_k, dim3(1), dim3(256), 0, stream, parts, inv0);
    hipLaunchKernelGGL(frob_k, dim3(256), dim3(256), 0, stream, S1, BIG, parts);
    hipLaunchKernelGGL(frob_fin_k, dim3(1), dim3(256), 0, stream, parts, inv1);
    hipLaunchKernelGGL(scalebf_k, dim3(1024), dim3(256), 0, stream, S0, XA, inv0, BIG);
    hipLaunchKernelGGL(tscalebf_k, dim3(64, 32), dim3(32, 8), 0, stream, S0, XT, inv0, 1024, 2048);
    hipLaunchKernelGGL(scalebf_k, dim3(1024), dim3(256), 0, stream, S1, XT + SB2, inv1, BIG);
    hipLaunchKernelGGL(tscalebf_k, dim3(32, 64), dim3(32, 8), 0, stream, S1, XA + SB2, inv1, 2048, 1024);

    unsigned short* Xc = XA;
    unsigned short* Xn = XB;
    for (int it = 0; it < 5; ++it) {
      // Ab = Xc @ Xc^T   (B operand row-major N x K = Xc itself)
      mgemm<5>(stream, Xc, Xc, Ab, nullptr, 1024, 1024, 2048, 2048, 2048, 1024, 0,
               0.f, 0.f, SB2, SB2, SB1, 0, 2);
      // Bb = NSc*(Ab@Ab) + NSb*Ab   (Ab symmetric -> B operand = Ab)
      mgemm<6>(stream, Ab, Ab, Bb, Ab, 1024, 1024, 1024, 1024, 1024, 1024, 1024,
               NSc, NSb, SB1, SB1, SB1, SB1, 2);
      // Xn = Bb@Xc + NSa*Xc  (B operand row-major N x K = Xc^T = XT)
      mgemm<6>(stream, Bb, XT, Xn, Xc, 1024, 2048, 1024, 1024, 1024, 2048, 2048,
               1.0f, NSa, SB1, SB2, SB2, SB2, 2);
      if (it < 4)
        hipLaunchKernelGGL(tbf_k, dim3(64, 32, 2), dim3(32, 8), 0, stream, Xn, XT);
      unsigned short* tmp = Xc; Xc = Xn; Xn = tmp;
    }
    hipLaunchKernelGGL(wupdbf_k, dim3(2048), dim3(256), 0, stream, W0, Xc, cpb, c, BIG);
    hipLaunchKernelGGL(wupd_t_bf_k, dim3(32, 64), dim3(32, 8), 0, stream, W1, Xc + SB2, cpb, c);
  }

  // ---- final: out = x + (retrieved @ Wout^T) * og ----
  gemm<0, 1, 4>(stream, retrv, Wout, out, 2048, 2048, 512, 512, 512, 2048,
                nullptr, x, 2048, 0.f, 0.f, og);
}

// Round 4
// 29366.553 us; speedup vs baseline: 3.1363x; 1.1044x over previous
//
#include <hip/hip_runtime.h>

// ---------------------------------------------------------------------------
// DeepMemoryLevel (ATLAS-style). B=2 S=1024 D=2048 M=512 P=1024 H=2048
// CHUNK=32 NC=32, tokens N=2048.
// Round 3: NS5 mgemm retiled 128x128 -> 64x64 (FM/FN template) so the small
// square GEMMs (1024x1024 out) get 512-1024 blocks instead of 128-256:
// fills all 256 CUs with 2-4 blocks/CU for barrier hiding.
// ---------------------------------------------------------------------------

#define TILE 64
#define KT 16

typedef __attribute__((ext_vector_type(8))) short s16x8;
typedef __attribute__((ext_vector_type(8))) unsigned short u16x8;
typedef __attribute__((ext_vector_type(4))) float f32x4;

__device__ __forceinline__ float gelu_f(float x) {
  return 0.5f * x * (1.0f + erff(x * 0.70710678118654752f));
}
__device__ __forceinline__ float gelu_grad_f(float x) {
  float cdf = 0.5f * (1.0f + erff(x * 0.70710678118654752f));
  float pdf = 0.3989422804014327f * expf(-0.5f * x * x);
  return cdf + x * pdf;
}
__device__ __forceinline__ float sigmoid_f(float x) { return 1.0f / (1.0f + expf(-x)); }

__device__ __forceinline__ unsigned short f2bf(float f) {
  union { float f; unsigned u; } v; v.f = f;
  unsigned r = (v.u + 0x7FFFu + ((v.u >> 16) & 1u)) >> 16;
  return (unsigned short)r;
}
__device__ __forceinline__ float bf2f(unsigned short h) {
  union { unsigned u; float f; } v; v.u = ((unsigned)h) << 16;
  return v.f;
}

__device__ __forceinline__ float block_reduce_sum(float v, float* red) {
  int t = threadIdx.x;
  red[t] = v; __syncthreads();
  for (int s = blockDim.x >> 1; s > 0; s >>= 1) {
    if (t < s) red[t] += red[t + s];
    __syncthreads();
  }
  float r = red[0];
  __syncthreads();
  return r;
}

// ---------------- bf16 MFMA GEMM (batched, TB=1 only) ----------------
// C[M,N] = A @ B^T_rowmajorNK + epilogue.  A: bf16 row-major M x K (lda).
// B: bf16 row-major N x K (ldb)  (i.e. math-B[k][n] = Bsrc[n][k]).
// EPI 5: C(bf16) = acc.   EPI 6: C(bf16) = c1*acc + c2*bf(E[m,n]).
// Tile = (32*FM) x (32*FN); 4 waves in 2x2; K multiple of 64.
// grid.z = batch, strides in elems.
#define MBK 64
#define MKP 72

// stage R x 64 bf16 tile (row-major, ld) into LDS (row stride MKP)
template<int R>
__device__ __forceinline__ void stage_tile(const unsigned short* __restrict__ src, int ld,
                                           unsigned short* __restrict__ dst, int t) {
  constexpr int TPR = 256 / R;    // threads per row
  constexpr int EPT = 64 / TPR;   // elems per thread
  constexpr int NL = EPT / 8;     // u16x8 loads
  const int row = t / TPR;
  const int koff = (t % TPR) * EPT;
  const unsigned short* s = src + (size_t)row * ld + koff;
  unsigned short* d = dst + row * MKP + koff;
#pragma unroll
  for (int i = 0; i < NL; ++i)
    *(u16x8*)(d + 8 * i) = *(const u16x8*)(s + 8 * i);
}

template<int FM, int FN, int EPI>
__global__ __launch_bounds__(256)
void mgemm_k(const unsigned short* __restrict__ Aq, const unsigned short* __restrict__ Bq,
             unsigned short* __restrict__ Cq, const unsigned short* __restrict__ Eq,
             int M, int N, int K, int lda, int ldb, int ldc, int lde,
             float c1, float c2, long sA, long sB, long sC, long sE) {
  constexpr int TM = 32 * FM, TN = 32 * FN;
  __shared__ __align__(16) unsigned short As[TM * MKP];
  __shared__ __align__(16) unsigned short Bs[TN * MKP];
  const int bz = blockIdx.z;
  const unsigned short* A = Aq + (size_t)bz * sA;
  const unsigned short* B = Bq + (size_t)bz * sB;
  const unsigned short* E = Eq + (size_t)bz * sE;
  unsigned short* C = Cq + (size_t)bz * sC;
  const int t = threadIdx.x;
  const int m0 = blockIdx.y * TM, n0 = blockIdx.x * TN;
  const int wave = t >> 6, lane = t & 63;
  const int wm = (wave >> 1) * (TM / 2), wn = (wave & 1) * (TN / 2);
  const int l15 = lane & 15, l4 = lane >> 4;

  f32x4 acc[FM][FN];
#pragma unroll
  for (int i = 0; i < FM; ++i)
#pragma unroll
    for (int j = 0; j < FN; ++j) acc[i][j] = (f32x4){0.f, 0.f, 0.f, 0.f};

  for (int k0 = 0; k0 < K; k0 += MBK) {
    stage_tile<TM>(A + (size_t)m0 * lda + k0, lda, As, t);
    stage_tile<TN>(B + (size_t)n0 * ldb + k0, ldb, Bs, t);
    __syncthreads();
#pragma unroll
    for (int ks = 0; ks < 2; ++ks) {
      s16x8 af[FM], bfr[FN];
#pragma unroll
      for (int mi = 0; mi < FM; ++mi)
        af[mi] = *(const s16x8*)&As[(wm + mi * 16 + l15) * MKP + ks * 32 + l4 * 8];
#pragma unroll
      for (int ni = 0; ni < FN; ++ni)
        bfr[ni] = *(const s16x8*)&Bs[(wn + ni * 16 + l15) * MKP + ks * 32 + l4 * 8];
#pragma unroll
      for (int mi = 0; mi < FM; ++mi)
#pragma unroll
        for (int ni = 0; ni < FN; ++ni)
          acc[mi][ni] = __builtin_amdgcn_mfma_f32_16x16x32_bf16(af[mi], bfr[ni], acc[mi][ni], 0, 0, 0);
    }
    __syncthreads();
  }

#pragma unroll
  for (int mi = 0; mi < FM; ++mi) {
#pragma unroll
    for (int i = 0; i < 4; ++i) {
      int row = m0 + wm + mi * 16 + l4 * 4 + i;
#pragma unroll
      for (int ni = 0; ni < FN; ++ni) {
        int col = n0 + wn + ni * 16 + l15;
        float v = acc[mi][ni][i];
        if constexpr (EPI == 6) v = c1 * v + c2 * bf2f(E[(size_t)row * lde + col]);
        C[(size_t)row * ldc + col] = f2bf(v);
      }
    }
  }
}

template<int FM, int FN, int EPI>
static void mgemm(hipStream_t s, const unsigned short* A, const unsigned short* B,
                  unsigned short* C, const unsigned short* E,
                  int M, int N, int K, int lda, int ldb, int ldc, int lde,
                  float c1, float c2, long sA, long sB, long sC, long sE, int batch) {
  dim3 g(N / (32 * FN), M / (32 * FM), batch), b(256);
  hipLaunchKernelGGL((mgemm_k<FM, FN, EPI>), g, b, 0, s, A, B, C, E, M, N, K,
                     lda, ldb, ldc, lde, c1, c2, sA, sB, sC, sE);
}

// ---------------- f32 GEMM (vector ALU) ----------------
// C[M,N] = op(A)@op(B). TA=0: A=(M,K); TA=1: A=(K,M). TB=0: B=(K,N); TB=1: B=(N,K).
// AG: chunk-gather rows of A; CS: scatter C rows; KW: B rows scaled by kw[k].
// EPI: 0 none | 1 gelu | 3 out=cp[3c+1]*C_old - cp[3c]*acc | 4 out=emat[m,n]+acc*erow[m]
template<int TA, int TB, int EPI, int AG, int CS, int KW>
__global__ __launch_bounds__(256)
void gemm_k(const float* __restrict__ A, const float* __restrict__ B,
            float* __restrict__ C, int M, int N, int K,
            int lda, int ldb, int ldc,
            const float* __restrict__ kw,
            const float* __restrict__ emat, int lde,
            float c1, float c2,
            const float* __restrict__ erow,
            const float* __restrict__ cp, int cidx, int cbase) {
  __shared__ float As[KT][TILE + 4];
  __shared__ float Bs[KT][TILE + 4];
  const int t = threadIdx.x;
  const int tx = t & 15, ty = t >> 4;
  const int n0 = blockIdx.x * TILE, m0 = blockIdx.y * TILE;
  float acc[4][4] = {};

  for (int k0 = 0; k0 < K; k0 += KT) {
#pragma unroll
    for (int i = 0; i < 4; ++i) {
      int idx = t + i * 256;
      if constexpr (TA == 0) {
        int mm = idx >> 4, kk = idx & 15;
        int row = m0 + mm;
        if constexpr (AG) row = ((row >> 5) << 10) + cbase + (row & 31);
        As[kk][mm] = A[(size_t)row * lda + (k0 + kk)];
      } else {
        int kk = idx >> 6, mm = idx & 63;
        int row = k0 + kk;
        if constexpr (AG) row = ((row >> 5) << 10) + cbase + (row & 31);
        As[kk][mm] = A[(size_t)row * lda + (m0 + mm)];
      }
    }
#pragma unroll
    for (int i = 0; i < 4; ++i) {
      int idx = t + i * 256;
      int kk, nn; float v;
      if constexpr (TB == 0) {
        kk = idx >> 6; nn = idx & 63;
        v = B[(size_t)(k0 + kk) * ldb + (n0 + nn)];
      } else {
        kk = idx & 15; nn = idx >> 4;
        v = B[(size_t)(n0 + nn) * ldb + (k0 + kk)];
      }
      if constexpr (KW) v *= kw[k0 + kk];
      Bs[kk][nn] = v;
    }
    __syncthreads();
#pragma unroll
    for (int kk = 0; kk < KT; ++kk) {
      const float4 av = *(const float4*)&As[kk][ty * 4];
      const float4 bv = *(const float4*)&Bs[kk][tx * 4];
      float aa[4] = {av.x, av.y, av.z, av.w};
      float bb[4] = {bv.x, bv.y, bv.z, bv.w};
#pragma unroll
      for (int i = 0; i < 4; ++i)
#pragma unroll
        for (int j = 0; j < 4; ++j) acc[i][j] += aa[i] * bb[j];
    }
    __syncthreads();
  }

#pragma unroll
  for (int i = 0; i < 4; ++i) {
    int m = m0 + ty * 4 + i;
    int crow = m;
    if constexpr (CS) crow = ((m >> 5) << 10) + cbase + (m & 31);
#pragma unroll
    for (int j = 0; j < 4; ++j) {
      int n = n0 + tx * 4 + j;
      float v = acc[i][j];
      if constexpr (EPI == 1) {
        v = gelu_f(v);
      } else if constexpr (EPI == 3) {
        float lr = cp[cidx * 3 + 0], mo = cp[cidx * 3 + 1];
        v = mo * C[(size_t)crow * ldc + n] - lr * v;
      } else if constexpr (EPI == 4) {
        v = emat[(size_t)m * lde + n] + v * erow[m];
      }
      C[(size_t)crow * ldc + n] = v;
    }
  }
}

// ---------------- elementwise / reductions ----------------

__global__ __launch_bounds__(256) void polynorm_k(const float* __restrict__ lin,
                                                  float* __restrict__ outp) {
  __shared__ float red[256];
  int n = blockIdx.x, t = threadIdx.x;
  float s = 0.f;
  for (int f = t; f < 512; f += 256) { float v = lin[(size_t)n * 512 + f]; s += v * v; }
  float tot = block_reduce_sum(s, red);
  float sc = 1.0f / fmaxf(sqrtf(tot), 1e-12f);
  const float is2 = 0.70710678118654752f;
  for (int f = t; f < 512; f += 256) {
    float v = lin[(size_t)n * 512 + f] * sc;
    outp[(size_t)n * 1024 + f] = v * is2;
    outp[(size_t)n * 1024 + 512 + f] = v * v * is2;
  }
}

__global__ __launch_bounds__(256) void gates_k(const float* __restrict__ x,
    const float* __restrict__ wlr, const float* __restrict__ blr,
    const float* __restrict__ wmom, const float* __restrict__ bmom,
    const float* __restrict__ wdec, const float* __restrict__ bdec,
    const float* __restrict__ wgate, const float* __restrict__ bgate,
    float* __restrict__ lrv, float* __restrict__ momv,
    float* __restrict__ decv, float* __restrict__ og) {
  __shared__ float red[256];
  int n = blockIdx.x, t = threadIdx.x;
  float s0 = 0.f, s1 = 0.f, s2 = 0.f, s3 = 0.f;
  for (int d = t; d < 2048; d += 256) {
    float xv = x[(size_t)n * 2048 + d];
    s0 += xv * wlr[d]; s1 += xv * wmom[d]; s2 += xv * wdec[d]; s3 += xv * wgate[d];
  }
  float r0 = block_reduce_sum(s0, red);
  float r1 = block_reduce_sum(s1, red);
  float r2 = block_reduce_sum(s2, red);
  float r3 = block_reduce_sum(s3, red);
  if (t == 0) {
    lrv[n] = sigmoid_f(r0 + blr[0]);
    momv[n] = sigmoid_f(r1 + bmom[0]);
    decv[n] = sigmoid_f(r2 + bdec[0]);
    og[n] = sigmoid_f(r3 + bgate[0]);
  }
}

__global__ void chunk_means_k(const float* __restrict__ lrv, const float* __restrict__ momv,
                              const float* __restrict__ decv, float* __restrict__ cp) {
  int c = blockIdx.x, t = threadIdx.x;  // 64 threads
  int n = ((t >> 5) << 10) + c * 32 + (t & 31);
  float a = lrv[n], b = momv[n], d = decv[n];
  for (int off = 32; off > 0; off >>= 1) {
    a += __shfl_down(a, off);
    b += __shfl_down(b, off);
    d += __shfl_down(d, off);
  }
  if (t == 0) {
    cp[c * 3 + 0] = a * (1.f / 64.f);
    cp[c * 3 + 1] = b * (1.f / 64.f);
    cp[c * 3 + 2] = d * (1.f / 64.f);
  }
}

__global__ __launch_bounds__(256) void gelu_fb_k(const float* __restrict__ h,
                                                 float* __restrict__ a,
                                                 float* __restrict__ gp, int n) {
  for (int i = blockIdx.x * 256 + threadIdx.x; i < n; i += gridDim.x * 256) {
    float v = h[i];
    a[i] = gelu_f(v);
    gp[i] = gelu_grad_f(v);
  }
}

__global__ __launch_bounds__(256) void resid_k(const float* __restrict__ pred,
                                               const float* __restrict__ vexp,
                                               float* __restrict__ r, int cbase) {
  int idx = blockIdx.x * 256 + threadIdx.x;  // 65536 total
  int i = idx >> 10, p = idx & 1023;
  int row = ((i >> 5) << 10) + cbase + (i & 31);
  r[idx] = 2.0f * (pred[idx] - vexp[(size_t)row * 1024 + p]);
}

__global__ __launch_bounds__(256) void mul_k(const float* __restrict__ a,
                                             const float* __restrict__ b,
                                             float* __restrict__ c, int n) {
  for (int i = blockIdx.x * 256 + threadIdx.x; i < n; i += gridDim.x * 256) c[i] = a[i] * b[i];
}

__global__ __launch_bounds__(256) void sampnorm_k(const float* __restrict__ kp,
                                                  const float* __restrict__ dh,
                                                  const float* __restrict__ a,
                                                  const float* __restrict__ r,
                                                  float* __restrict__ w0inv,
                                                  float* __restrict__ w1inv, int cbase) {
  __shared__ float red[256];
  int i = blockIdx.x, t = threadIdx.x;
  int row = ((i >> 5) << 10) + cbase + (i & 31);
  float sk = 0.f, sr = 0.f, sdh = 0.f, sa = 0.f;
  for (int p = t; p < 1024; p += 256) {
    float v = kp[(size_t)row * 1024 + p]; sk += v * v;
    v = r[(size_t)i * 1024 + p]; sr += v * v;
  }
  for (int h = t; h < 2048; h += 256) {
    float v = dh[(size_t)i * 2048 + h]; sdh += v * v;
    v = a[(size_t)i * 2048 + h]; sa += v * v;
  }
  float tk = block_reduce_sum(sk, red);
  float tdh = block_reduce_sum(sdh, red);
  float ta = block_reduce_sum(sa, red);
  float tr = block_reduce_sum(sr, red);
  if (t == 0) {
    float n0 = fmaxf(sqrtf(tk) * sqrtf(tdh), 1e-8f);
    w0inv[i] = 1.0f / (64.0f * fmaxf(n0 * 0.1f, 1.0f));
    float n1 = fmaxf(sqrtf(ta) * sqrtf(tr), 1e-8f);
    w1inv[i] = 1.0f / (64.0f * fmaxf(n1 * 0.1f, 1.0f));
  }
}

__global__ __launch_bounds__(256) void frob_k(const float* __restrict__ s, int n,
                                              float* __restrict__ parts) {
  __shared__ float red[256];
  float acc = 0.f;
  for (int i = blockIdx.x * 256 + threadIdx.x; i < n; i += gridDim.x * 256) {
    float v = s[i]; acc += v * v;
  }
  float r = block_reduce_sum(acc, red);
  if (threadIdx.x == 0) parts[blockIdx.x] = r;
}

__global__ __launch_bounds__(256) void frob_fin_k(const float* __restrict__ parts,
                                                  float* __restrict__ inv) {
  __shared__ float red[256];
  float r = block_reduce_sum(parts[threadIdx.x], red);
  if (threadIdx.x == 0) *inv = 1.0f / (sqrtf(r) + 1e-7f);
}

// dst_bf16 = src_f32 * (*inv)
__global__ __launch_bounds__(256) void scalebf_k(const float* __restrict__ src,
                                                 unsigned short* __restrict__ dst,
                                                 const float* __restrict__ inv, int n) {
  float s = *inv;
  for (int i = blockIdx.x * 256 + threadIdx.x; i < n; i += gridDim.x * 256)
    dst[i] = f2bf(src[i] * s);
}

// out_bf16[C x R] = (in_f32[R x C])^T * (*inv)
__global__ void tscalebf_k(const float* __restrict__ in, unsigned short* __restrict__ out,
                           const float* __restrict__ inv, int R, int C) {
  __shared__ float tile[32][33];
  float s = *inv;
  int c0 = blockIdx.x * 32, r0 = blockIdx.y * 32;
  int tx = threadIdx.x, ty = threadIdx.y;
#pragma unroll
  for (int j = 0; j < 4; ++j)
    tile[ty + 8 * j][tx] = in[(size_t)(r0 + ty + 8 * j) * C + c0 + tx];
  __syncthreads();
#pragma unroll
  for (int j = 0; j < 4; ++j)
    out[(size_t)(c0 + ty + 8 * j) * R + r0 + tx] = f2bf(tile[tx][ty + 8 * j] * s);
}

// batched bf16 transpose: in[2][1024][2048] -> out[2][2048][1024]
__global__ void tbf_k(const unsigned short* __restrict__ in, unsigned short* __restrict__ out) {
  __shared__ unsigned short tile[32][33];
  size_t bo = (size_t)blockIdx.z * 2097152;
  int c0 = blockIdx.x * 32, r0 = blockIdx.y * 32;
  int tx = threadIdx.x, ty = threadIdx.y;
#pragma unroll
  for (int j = 0; j < 4; ++j)
    tile[ty + 8 * j][tx] = in[bo + (size_t)(r0 + ty + 8 * j) * 2048 + c0 + tx];
  __syncthreads();
#pragma unroll
  for (int j = 0; j < 4; ++j)
    out[bo + (size_t)(c0 + ty + 8 * j) * 1024 + r0 + tx] = tile[tx][ty + 8 * j];
}

// W0 = (1-dec)*W0 + lr*bf(X)
__global__ __launch_bounds__(256) void wupdbf_k(float* __restrict__ W,
                                                const unsigned short* __restrict__ X,
                                                const float* __restrict__ cp, int cidx, int n) {
  float lr = cp[cidx * 3 + 0], om = 1.0f - cp[cidx * 3 + 2];
  for (int i = blockIdx.x * 256 + threadIdx.x; i < n; i += gridDim.x * 256)
    W[i] = om * W[i] + lr * bf2f(X[i]);
}

// W1[h][p] = (1-dec)*W1[h][p] + lr*bf(X[p][h])   (X: 1024x2048 bf16, W1: 2048x1024 f32)
__global__ void wupd_t_bf_k(float* __restrict__ W1, const unsigned short* __restrict__ X,
                            const float* __restrict__ cp, int cidx) {
  __shared__ float tile[32][33];
  float lr = cp[cidx * 3 + 0], om = 1.0f - cp[cidx * 3 + 2];
  int p0 = blockIdx.x * 32, h0 = blockIdx.y * 32;
  int tx = threadIdx.x, ty = threadIdx.y;
#pragma unroll
  for (int j = 0; j < 4; ++j)
    tile[ty + 8 * j][tx] = bf2f(X[(size_t)(p0 + ty + 8 * j) * 2048 + h0 + tx]);
  __syncthreads();
#pragma unroll
  for (int j = 0; j < 4; ++j) {
    size_t idx = (size_t)(h0 + ty + 8 * j) * 1024 + p0 + tx;
    W1[idx] = om * W1[idx] + lr * tile[tx][ty + 8 * j];
  }
}

// ---------------- host ----------------

template<int TA, int TB, int EPI, int AG = 0, int CS = 0, int KW = 0>
static void gemm(hipStream_t s, const float* A, const float* B, float* C,
                 int M, int N, int K, int lda, int ldb, int ldc,
                 const float* kw = nullptr, const float* emat = nullptr, int lde = 0,
                 float c1 = 0.f, float c2 = 0.f, const float* erow = nullptr,
                 const float* cp = nullptr, int cidx = 0, int cbase = 0) {
  dim3 g(N / TILE, M / TILE), b(256);
  hipLaunchKernelGGL((gemm_k<TA, TB, EPI, AG, CS, KW>), g, b, 0, s,
                     A, B, C, M, N, K, lda, ldb, ldc, kw, emat, lde, c1, c2, erow, cp, cidx, cbase);
}

extern "C" void kernel_launch(void* const* d_in, const int* in_sizes, int n_in,
                              void* d_out, int out_size, void* d_ws, size_t ws_size,
                              hipStream_t stream) {
  const float* x = (const float*)d_in[0];
  const float* Wk = (const float*)d_in[1];
  const float* Wv = (const float*)d_in[2];
  const float* Wq = (const float*)d_in[3];
  const float* Wout = (const float*)d_in[4];
  const float* w_lr = (const float*)d_in[5];
  const float* b_lr = (const float*)d_in[6];
  const float* w_mom = (const float*)d_in[7];
  const float* b_mom = (const float*)d_in[8];
  const float* w_dec = (const float*)d_in[9];
  const float* b_dec = (const float*)d_in[10];
  const float* w_gate = (const float*)d_in[11];
  const float* b_gate = (const float*)d_in[12];
  const float* Wmem0 = (const float*)d_in[13];
  const float* Wmem1 = (const float*)d_in[14];
  const float* Wmemout = (const float*)d_in[15];
  const float* Wvexp = (const float*)d_in[16];
  float* out = (float*)d_out;

  const int BIG = 2097152;   // 1024*2048
  const int MED = 1048576;
  const int SM = 131072;     // 64*2048
  const long SB2 = 2097152, SB1 = 1048576;
  float* ws = (float*)d_ws;
  float* kp    = ws;                 // (2048,1024) f32
  float* qp    = kp + BIG;
  float* vexp  = qp + BIG;
  float* W0    = vexp + BIG;         // (1024,2048) f32
  float* W1    = W0 + BIG;           // (2048,1024) f32
  float* S0    = W1 + BIG;
  float* S1    = S0 + BIG;
  float* bfreg = S1 + BIG;           // 6M floats of bf16 buffers
  unsigned short* XA = (unsigned short*)bfreg;   // [2][1024][2048] bf16
  unsigned short* XB = XA + 2 * BIG;             // [2][1024][2048] bf16
  unsigned short* XT = XB + 2 * BIG;             // [2][2048][1024] bf16
  float* lin   = bfreg + 3 * (long)BIG;  // (2048,512) f32 (prologue only)
  float* vlin  = lin + MED;              // (2048,512) f32 (prologue only)
  unsigned short* Ab = (unsigned short*)lin;     // [2][1024][1024] bf16 (loop)
  unsigned short* Bb = (unsigned short*)vlin;    // [2][1024][1024] bf16 (loop)
  float* retrv = vlin + MED;         // (2048,512)
  float* ha    = retrv + MED;        // (64,2048)
  float* hbuf  = ha + SM;
  float* abuf  = hbuf + SM;
  float* gpbuf = abuf + SM;
  float* DAbuf = gpbuf + SM;
  float* dhbuf = DAbuf + SM;
  float* predb = dhbuf + SM;         // (64,1024)
  float* rbuf  = predb + 65536;
  float* og    = rbuf + 65536;
  float* lrv   = og + 2048;
  float* momv  = lrv + 2048;
  float* decv  = momv + 2048;
  float* cpb   = decv + 2048;        // 32*3
  float* w0inv = cpb + 128;
  float* w1inv = w0inv + 64;
  float* parts = w1inv + 64;         // 256
  float* inv0  = parts + 256;
  float* inv1  = inv0 + 1;
  (void)n_in; (void)in_sizes; (void)out_size;
  if (ws_size < (size_t)(25043464) * sizeof(float)) return;

  const float NSa = 3.4445f, NSb = -4.7750f, NSc = 2.0315f;

  hipMemcpyAsync(W0, Wmem0, (size_t)BIG * 4, hipMemcpyDeviceToDevice, stream);
  hipMemcpyAsync(W1, Wmem1, (size_t)BIG * 4, hipMemcpyDeviceToDevice, stream);
  hipMemsetAsync(S0, 0, (size_t)BIG * 4, stream);
  hipMemsetAsync(S1, 0, (size_t)BIG * 4, stream);

  // ---- projections + poly ----
  gemm<0, 1, 0>(stream, x, Wk, lin, 2048, 512, 2048, 2048, 2048, 512);
  hipLaunchKernelGGL(polynorm_k, dim3(2048), dim3(256), 0, stream, lin, kp);
  gemm<0, 1, 0>(stream, x, Wq, lin, 2048, 512, 2048, 2048, 2048, 512);
  hipLaunchKernelGGL(polynorm_k, dim3(2048), dim3(256), 0, stream, lin, qp);
  gemm<0, 1, 0>(stream, x, Wv, vlin, 2048, 512, 2048, 2048, 2048, 512);
  gemm<0, 0, 0>(stream, vlin, Wvexp, vexp, 2048, 1024, 512, 512, 1024, 1024);

  // ---- gates + chunk means ----
  hipLaunchKernelGGL(gates_k, dim3(2048), dim3(256), 0, stream, x,
                     w_lr, b_lr, w_mom, b_mom, w_dec, b_dec, w_gate, b_gate,
                     lrv, momv, decv, og);
  hipLaunchKernelGGL(chunk_means_k, dim3(32), dim3(64), 0, stream, lrv, momv, decv, cpb);

  // ---- sequential chunk scan ----
  for (int c = 0; c < 32; ++c) {
    const int cbase = c * 32;
    // retrieval with pre-update params
    gemm<0, 0, 1, 1>(stream, qp, W0, ha, 64, 2048, 1024, 1024, 2048, 2048,
                     nullptr, nullptr, 0, 0.f, 0.f, nullptr, nullptr, 0, cbase);
    gemm<0, 0, 0>(stream, ha, W1, predb, 64, 1024, 2048, 2048, 1024, 1024);
    gemm<0, 0, 0, 0, 1>(stream, predb, Wmemout, retrv, 64, 512, 1024, 1024, 512, 512,
                        nullptr, nullptr, 0, 0.f, 0.f, nullptr, nullptr, 0, cbase);
    // grads (rank-1 per-sample -> weighted K=64 GEMMs)
    gemm<0, 0, 0, 1>(stream, kp, W0, hbuf, 64, 2048, 1024, 1024, 2048, 2048,
                     nullptr, nullptr, 0, 0.f, 0.f, nullptr, nullptr, 0, cbase);
    hipLaunchKernelGGL(gelu_fb_k, dim3(512), dim3(256), 0, stream, hbuf, abuf, gpbuf, SM);
    gemm<0, 0, 0>(stream, abuf, W1, predb, 64, 1024, 2048, 2048, 1024, 1024);
    hipLaunchKernelGGL(resid_k, dim3(256), dim3(256), 0, stream, predb, vexp, rbuf, cbase);
    gemm<0, 1, 0>(stream, rbuf, W1, DAbuf, 64, 2048, 1024, 1024, 1024, 2048);
    hipLaunchKernelGGL(mul_k, dim3(512), dim3(256), 0, stream, DAbuf, gpbuf, dhbuf, SM);
    hipLaunchKernelGGL(sampnorm_k, dim3(64), dim3(256), 0, stream, kp, dhbuf, abuf, rbuf,
                       w0inv, w1inv, cbase);
    gemm<1, 0, 3, 1, 0, 1>(stream, kp, dhbuf, S0, 1024, 2048, 64, 1024, 2048, 2048,
                           w0inv, nullptr, 0, 0.f, 0.f, nullptr, cpb, c, cbase);
    gemm<1, 0, 3, 0, 0, 1>(stream, abuf, rbuf, S1, 2048, 1024, 64, 2048, 1024, 1024,
                           w1inv, nullptr, 0, 0.f, 0.f, nullptr, cpb, c, 0);

    // ---- batched NS5 (bf16 MFMA): batch0 = S0 (1024x2048), batch1 = S1^T ----
    hipLaunchKernelGGL(frob_k, dim3(256), dim3(256), 0, stream, S0, BIG, parts);
    hipLaunchKernelGGL(frob_fin_k, dim3(1), dim3(256), 0, stream, parts, inv0);
    hipLaunchKernelGGL(frob_k, dim3(256), dim3(256), 0, stream, S1, BIG, parts);
    hipLaunchKernelGGL(frob_fin_k, dim3(1), dim3(256), 0, stream, parts, inv1);
    hipLaunchKernelGGL(scalebf_k, dim3(1024), dim3(256), 0, stream, S0, XA, inv0, BIG);
    hipLaunchKernelGGL(tscalebf_k, dim3(64, 32), dim3(32, 8), 0, stream, S0, XT, inv0, 1024, 2048);
    hipLaunchKernelGGL(scalebf_k, dim3(1024), dim3(256), 0, stream, S1, XT + SB2, inv1, BIG);
    hipLaunchKernelGGL(tscalebf_k, dim3(32, 64), dim3(32, 8), 0, stream, S1, XA + SB2, inv1, 2048, 1024);

    unsigned short* Xc = XA;
    unsigned short* Xn = XB;
    for (int it = 0; it < 5; ++it) {
      // Ab = Xc @ Xc^T   (B operand row-major N x K = Xc itself)
      mgemm<2, 2, 5>(stream, Xc, Xc, Ab, nullptr, 1024, 1024, 2048, 2048, 2048, 1024, 0,
                     0.f, 0.f, SB2, SB2, SB1, 0, 2);
      // Bb = NSc*(Ab@Ab) + NSb*Ab   (Ab symmetric -> B operand = Ab)
      mgemm<2, 2, 6>(stream, Ab, Ab, Bb, Ab, 1024, 1024, 1024, 1024, 1024, 1024, 1024,
                     NSc, NSb, SB1, SB1, SB1, SB1, 2);
      // Xn = Bb@Xc + NSa*Xc  (B operand row-major N x K = Xc^T = XT)
      mgemm<2, 2, 6>(stream, Bb, XT, Xn, Xc, 1024, 2048, 1024, 1024, 1024, 2048, 2048,
                     1.0f, NSa, SB1, SB2, SB2, SB2, 2);
      if (it < 4)
        hipLaunchKernelGGL(tbf_k, dim3(64, 32, 2), dim3(32, 8), 0, stream, Xn, XT);
      unsigned short* tmp = Xc; Xc = Xn; Xn = tmp;
    }
    hipLaunchKernelGGL(wupdbf_k, dim3(2048), dim3(256), 0, stream, W0, Xc, cpb, c, BIG);
    hipLaunchKernelGGL(wupd_t_bf_k, dim3(32, 64), dim3(32, 8), 0, stream, W1, Xc + SB2, cpb, c);
  }

  // ---- final: out = x + (retrieved @ Wout^T) * og ----
  gemm<0, 1, 4>(stream, retrv, Wout, out, 2048, 2048, 512, 512, 512, 2048,
                nullptr, x, 2048, 0.f, 0.f, og);
}

// Round 5
// 20243.068 us; speedup vs baseline: 4.5499x; 1.4507x over previous
//
#include <hip/hip_runtime.h>

// ---------------------------------------------------------------------------
// DeepMemoryLevel (ATLAS-style). B=2 S=1024 D=2048 M=512 P=1024 H=2048
// CHUNK=32 NC=32, tokens N=2048.
// Round 5: (a) 1-wave 64x64 MFMA GEMM blocks (2:1 MFMA:ds ratio, 8 blocks/CU);
// (b) whole chunk path on MFMA with chunk-major layout + fused epilogues.
// W0/W1 kept as f32 masters; bf16 (+transposed) copies refreshed on update.
// ---------------------------------------------------------------------------

typedef unsigned short us;
typedef __attribute__((ext_vector_type(8))) short s16x8;
typedef __attribute__((ext_vector_type(8))) unsigned short u16x8;
typedef __attribute__((ext_vector_type(4))) float f32x4;

#define MKP 72

__device__ __forceinline__ float gelu_f(float x) {
  return 0.5f * x * (1.0f + erff(x * 0.70710678118654752f));
}
__device__ __forceinline__ float gelu_grad_f(float x) {
  float cdf = 0.5f * (1.0f + erff(x * 0.70710678118654752f));
  float pdf = 0.3989422804014327f * expf(-0.5f * x * x);
  return cdf + x * pdf;
}
__device__ __forceinline__ float sigmoid_f(float x) { return 1.0f / (1.0f + expf(-x)); }

__device__ __forceinline__ us f2bf(float f) {
  union { float f; unsigned u; } v; v.f = f;
  unsigned r = (v.u + 0x7FFFu + ((v.u >> 16) & 1u)) >> 16;
  return (us)r;
}
__device__ __forceinline__ float bf2f(us h) {
  union { unsigned u; float f; } v; v.u = ((unsigned)h) << 16;
  return v.f;
}
// token-major index n -> chunk-major row
__device__ __forceinline__ int cm_map(int n) {
  return ((n & 1023) >> 5) * 64 + (n >> 10) * 32 + (n & 31);
}

__device__ __forceinline__ float block_reduce_sum(float v, float* red) {
  int t = threadIdx.x;
  red[t] = v; __syncthreads();
  for (int s = blockDim.x >> 1; s > 0; s >>= 1) {
    if (t < s) red[t] += red[t + s];
    __syncthreads();
  }
  float r = red[0];
  __syncthreads();
  return r;
}

// ---------------- 1-wave 64x64 bf16 MFMA GEMM ----------------
// C[M,N] = A @ Bsrc^T, Bsrc row-major N x K (ldb).
// TA=0: A row-major M x K (lda). TA=1: A row-major K x M (lda = M-stride).
// DUAL: block rows [64,128) read from A2 (row-64). AG: global A row = cm_map.
// EPI: 5  C us = acc
//      6  C us = c1*acc + c2*bf(E_us[m,n])           (batched NS)
//      7  C f32 = acc
//      8  C us = gelu(acc); if m0>=64: C2 f32[(m-64),n] = gelu'(acc)
//      9  C us: m0<64 -> acc ; else -> 2*(acc - E_f32[(m-64),n])
//      13 C f32 = acc * E_f32[m,n]
//      14 C f32 = cp[3ci+1]*C_old - cp[3ci]*acc
//      15 C f32 = FX[m,n] + acc*OG[m]
//      17 C f32, row scattered to cm_map(m)
template<int EPI, int TA, int DUAL, int AG>
__global__ __launch_bounds__(64)
void mg_k(const us* __restrict__ Aq, const us* __restrict__ A2,
          const us* __restrict__ Bq, void* __restrict__ Cq,
          void* __restrict__ C2, const void* __restrict__ Eq,
          const float* __restrict__ FX, const float* __restrict__ OG,
          const float* __restrict__ cp, int cidx,
          int M, int N, int K, int lda, int ldb, int ldc, int lde,
          float c1, float c2, long sA, long sB, long sC, long sE) {
  __shared__ __align__(16) us As[64 * MKP];
  __shared__ __align__(16) us Bs[64 * MKP];
  const int bz = blockIdx.z;
  const us* A = Aq + (size_t)bz * sA;
  const us* B = Bq + (size_t)bz * sB;
  const int t = threadIdx.x;
  const int m0 = blockIdx.y * 64, n0 = blockIdx.x * 64;
  if constexpr (DUAL) { if (m0 >= 64) A = A2; }
  const int mA0 = DUAL ? (m0 & 63) : m0;
  const int l15 = t & 15, l4 = t >> 4;

  f32x4 acc[4][4];
#pragma unroll
  for (int i = 0; i < 4; ++i)
#pragma unroll
    for (int j = 0; j < 4; ++j) acc[i][j] = (f32x4){0.f, 0.f, 0.f, 0.f};

  const int srw = t >> 3;          // 0..7 base row / k
  const int sck = (t & 7) * 8;     // 0..56 col chunk

  for (int k0 = 0; k0 < K; k0 += 64) {
    if constexpr (TA == 0) {
#pragma unroll
      for (int p = 0; p < 8; ++p) {
        int row = srw + p * 8;
        int srow = mA0 + row;
        if constexpr (AG) srow = cm_map(m0 + row);
        u16x8 v = *(const u16x8*)(A + (size_t)srow * lda + k0 + sck);
        *(u16x8*)&As[row * MKP + sck] = v;
      }
    } else {
#pragma unroll
      for (int p = 0; p < 8; ++p) {
        int kk = srw + p * 8;
        u16x8 v = *(const u16x8*)(A + (size_t)(k0 + kk) * lda + mA0 + sck);
#pragma unroll
        for (int j = 0; j < 8; ++j) As[(sck + j) * MKP + kk] = v[j];
      }
    }
#pragma unroll
    for (int p = 0; p < 8; ++p) {
      int row = srw + p * 8;
      u16x8 v = *(const u16x8*)(B + (size_t)(n0 + row) * ldb + k0 + sck);
      *(u16x8*)&Bs[row * MKP + sck] = v;
    }
    __syncthreads();
#pragma unroll
    for (int ks = 0; ks < 2; ++ks) {
      s16x8 af[4], bf[4];
#pragma unroll
      for (int mi = 0; mi < 4; ++mi)
        af[mi] = *(const s16x8*)&As[(mi * 16 + l15) * MKP + ks * 32 + l4 * 8];
#pragma unroll
      for (int ni = 0; ni < 4; ++ni)
        bf[ni] = *(const s16x8*)&Bs[(ni * 16 + l15) * MKP + ks * 32 + l4 * 8];
#pragma unroll
      for (int mi = 0; mi < 4; ++mi)
#pragma unroll
        for (int ni = 0; ni < 4; ++ni)
          acc[mi][ni] = __builtin_amdgcn_mfma_f32_16x16x32_bf16(af[mi], bf[ni], acc[mi][ni], 0, 0, 0);
    }
    __syncthreads();
  }

#pragma unroll
  for (int mi = 0; mi < 4; ++mi) {
#pragma unroll
    for (int i = 0; i < 4; ++i) {
      int grow = m0 + mi * 16 + l4 * 4 + i;
#pragma unroll
      for (int ni = 0; ni < 4; ++ni) {
        int col = n0 + ni * 16 + l15;
        float v = acc[mi][ni][i];
        if constexpr (EPI == 5) {
          ((us*)Cq + bz * sC)[(size_t)grow * ldc + col] = f2bf(v);
        } else if constexpr (EPI == 6) {
          const us* E = (const us*)Eq + bz * sE;
          ((us*)Cq + bz * sC)[(size_t)grow * ldc + col] =
              f2bf(c1 * v + c2 * bf2f(E[(size_t)grow * lde + col]));
        } else if constexpr (EPI == 7) {
          ((float*)Cq)[(size_t)grow * ldc + col] = v;
        } else if constexpr (EPI == 8) {
          ((us*)Cq)[(size_t)grow * ldc + col] = f2bf(gelu_f(v));
          if (m0 >= 64)
            ((float*)C2)[(size_t)(grow - 64) * ldc + col] = gelu_grad_f(v);
        } else if constexpr (EPI == 9) {
          if (m0 < 64)
            ((us*)Cq)[(size_t)grow * ldc + col] = f2bf(v);
          else
            ((us*)Cq)[(size_t)grow * ldc + col] =
                f2bf(2.0f * (v - ((const float*)Eq)[(size_t)(grow - 64) * lde + col]));
        } else if constexpr (EPI == 13) {
          ((float*)Cq)[(size_t)grow * ldc + col] =
              v * ((const float*)Eq)[(size_t)grow * lde + col];
        } else if constexpr (EPI == 14) {
          float* C = (float*)Cq;
          float old = C[(size_t)grow * ldc + col];
          C[(size_t)grow * ldc + col] = cp[cidx * 3 + 1] * old - cp[cidx * 3 + 0] * v;
        } else if constexpr (EPI == 15) {
          ((float*)Cq)[(size_t)grow * ldc + col] =
              FX[(size_t)grow * ldc + col] + v * OG[grow];
        } else if constexpr (EPI == 17) {
          int crow = cm_map(grow);
          ((float*)Cq)[(size_t)crow * ldc + col] = v;
        }
      }
    }
  }
}

template<int EPI, int TA = 0, int DUAL = 0, int AG = 0>
static void mg(hipStream_t st, const us* A, const us* A2, const us* B,
               void* C, void* C2, const void* E,
               const float* FX, const float* OG, const float* cp, int cidx,
               int M, int N, int K, int lda, int ldb, int ldc, int lde,
               float c1, float c2, long sA, long sB, long sC, long sE, int batch) {
  dim3 g(N / 64, M / 64, batch), b(64);
  hipLaunchKernelGGL((mg_k<EPI, TA, DUAL, AG>), g, b, 0, st, A, A2, B, C, C2, E,
                     FX, OG, cp, cidx, M, N, K, lda, ldb, ldc, lde, c1, c2, sA, sB, sC, sE);
}

// ---------------- conversions ----------------

__global__ __launch_bounds__(256) void conv_k(const float* __restrict__ in,
                                              us* __restrict__ out, int n) {
  for (int i = blockIdx.x * 256 + threadIdx.x; i < n; i += gridDim.x * 256)
    out[i] = f2bf(in[i]);
}

// out_bf16[C x R] = (in_f32[R x C])^T
__global__ void tconv_k(const float* __restrict__ in, us* __restrict__ out, int R, int C) {
  __shared__ float tile[32][33];
  int c0 = blockIdx.x * 32, r0 = blockIdx.y * 32;
  int tx = threadIdx.x, ty = threadIdx.y;
#pragma unroll
  for (int j = 0; j < 4; ++j)
    tile[ty + 8 * j][tx] = in[(size_t)(r0 + ty + 8 * j) * C + c0 + tx];
  __syncthreads();
#pragma unroll
  for (int j = 0; j < 4; ++j)
    out[(size_t)(c0 + ty + 8 * j) * R + r0 + tx] = f2bf(tile[tx][ty + 8 * j]);
}

// ---------------- elementwise / reductions ----------------

// per-token normalize + poly, writing bf16 chunk-major
__global__ __launch_bounds__(256) void polynorm2_k(const float* __restrict__ lin,
                                                   us* __restrict__ outp) {
  __shared__ float red[256];
  int n = blockIdx.x, t = threadIdx.x;
  int rowp = cm_map(n);
  float s = 0.f;
  for (int f = t; f < 512; f += 256) { float v = lin[(size_t)n * 512 + f]; s += v * v; }
  float tot = block_reduce_sum(s, red);
  float sc = 1.0f / fmaxf(sqrtf(tot), 1e-12f);
  const float is2 = 0.70710678118654752f;
  for (int f = t; f < 512; f += 256) {
    float v = lin[(size_t)n * 512 + f] * sc;
    outp[(size_t)rowp * 1024 + f] = f2bf(v * is2);
    outp[(size_t)rowp * 1024 + 512 + f] = f2bf(v * v * is2);
  }
}

__global__ __launch_bounds__(256) void gates_k(const float* __restrict__ x,
    const float* __restrict__ wlr, const float* __restrict__ blr,
    const float* __restrict__ wmom, const float* __restrict__ bmom,
    const float* __restrict__ wdec, const float* __restrict__ bdec,
    const float* __restrict__ wgate, const float* __restrict__ bgate,
    float* __restrict__ lrv, float* __restrict__ momv,
    float* __restrict__ decv, float* __restrict__ og) {
  __shared__ float red[256];
  int n = blockIdx.x, t = threadIdx.x;
  float s0 = 0.f, s1 = 0.f, s2 = 0.f, s3 = 0.f;
  for (int d = t; d < 2048; d += 256) {
    float xv = x[(size_t)n * 2048 + d];
    s0 += xv * wlr[d]; s1 += xv * wmom[d]; s2 += xv * wdec[d]; s3 += xv * wgate[d];
  }
  float r0 = block_reduce_sum(s0, red);
  float r1 = block_reduce_sum(s1, red);
  float r2 = block_reduce_sum(s2, red);
  float r3 = block_reduce_sum(s3, red);
  if (t == 0) {
    lrv[n] = sigmoid_f(r0 + blr[0]);
    momv[n] = sigmoid_f(r1 + bmom[0]);
    decv[n] = sigmoid_f(r2 + bdec[0]);
    og[n] = sigmoid_f(r3 + bgate[0]);
  }
}

__global__ void chunk_means_k(const float* __restrict__ lrv, const float* __restrict__ momv,
                              const float* __restrict__ decv, float* __restrict__ cp) {
  int c = blockIdx.x, t = threadIdx.x;  // 64 threads
  int n = ((t >> 5) << 10) + c * 32 + (t & 31);
  float a = lrv[n], b = momv[n], d = decv[n];
  for (int off = 32; off > 0; off >>= 1) {
    a += __shfl_down(a, off);
    b += __shfl_down(b, off);
    d += __shfl_down(d, off);
  }
  if (t == 0) {
    cp[c * 3 + 0] = a * (1.f / 64.f);
    cp[c * 3 + 1] = b * (1.f / 64.f);
    cp[c * 3 + 2] = d * (1.f / 64.f);
  }
}

// per-sample clip weights (chunk-major inputs)
__global__ __launch_bounds__(256) void sampnorm2_k(const us* __restrict__ kp_b,
                                                   const float* __restrict__ dh,
                                                   const us* __restrict__ hab,
                                                   const us* __restrict__ pr,
                                                   float* __restrict__ w0inv,
                                                   float* __restrict__ w1inv, int c) {
  __shared__ float red[256];
  int i = blockIdx.x, t = threadIdx.x;
  int row = c * 64 + i;
  float sk = 0.f, sr = 0.f, sdh = 0.f, sa = 0.f;
  for (int p = t; p < 1024; p += 256) {
    float v = bf2f(kp_b[(size_t)row * 1024 + p]); sk += v * v;
    v = bf2f(pr[(size_t)(64 + i) * 1024 + p]); sr += v * v;
  }
  for (int h = t; h < 2048; h += 256) {
    float v = dh[(size_t)i * 2048 + h]; sdh += v * v;
    v = bf2f(hab[(size_t)(64 + i) * 2048 + h]); sa += v * v;
  }
  float tk = block_reduce_sum(sk, red);
  float tdh = block_reduce_sum(sdh, red);
  float ta = block_reduce_sum(sa, red);
  float tr = block_reduce_sum(sr, red);
  if (t == 0) {
    float n0 = fmaxf(sqrtf(tk) * sqrtf(tdh), 1e-8f);
    w0inv[i] = 1.0f / (64.0f * fmaxf(n0 * 0.1f, 1.0f));
    float n1 = fmaxf(sqrtf(ta) * sqrtf(tr), 1e-8f);
    w1inv[i] = 1.0f / (64.0f * fmaxf(n1 * 0.1f, 1.0f));
  }
}

// out_bf16[C x 64] = (in[64 x C] * w[row])^T ; INF32 selects input dtype
template<int INF32>
__global__ void wtrans_k(const void* __restrict__ in, const float* __restrict__ w,
                         us* __restrict__ out, int C, int ldin) {
  __shared__ float tile[32][33];
  int c0 = blockIdx.x * 32, r0 = blockIdx.y * 32;
  int tx = threadIdx.x, ty = threadIdx.y;
#pragma unroll
  for (int j = 0; j < 4; ++j) {
    int r = r0 + ty + 8 * j, cc = c0 + tx;
    float v;
    if constexpr (INF32) v = ((const float*)in)[(size_t)r * ldin + cc];
    else v = bf2f(((const us*)in)[(size_t)r * ldin + cc]);
    tile[ty + 8 * j][tx] = v * w[r];
  }
  __syncthreads();
#pragma unroll
  for (int j = 0; j < 4; ++j)
    out[(size_t)(c0 + ty + 8 * j) * 64 + r0 + tx] = f2bf(tile[tx][ty + 8 * j]);
}

__global__ __launch_bounds__(256) void frob_k(const float* __restrict__ s, int n,
                                              float* __restrict__ parts) {
  __shared__ float red[256];
  float acc = 0.f;
  for (int i = blockIdx.x * 256 + threadIdx.x; i < n; i += gridDim.x * 256) {
    float v = s[i]; acc += v * v;
  }
  float r = block_reduce_sum(acc, red);
  if (threadIdx.x == 0) parts[blockIdx.x] = r;
}

__global__ __launch_bounds__(256) void frob_fin_k(const float* __restrict__ parts,
                                                  float* __restrict__ inv) {
  __shared__ float red[256];
  float r = block_reduce_sum(parts[threadIdx.x], red);
  if (threadIdx.x == 0) *inv = 1.0f / (sqrtf(r) + 1e-7f);
}

__global__ __launch_bounds__(256) void scalebf_k(const float* __restrict__ src,
                                                 us* __restrict__ dst,
                                                 const float* __restrict__ inv, int n) {
  float s = *inv;
  for (int i = blockIdx.x * 256 + threadIdx.x; i < n; i += gridDim.x * 256)
    dst[i] = f2bf(src[i] * s);
}

// out_bf16[C x R] = (in_f32[R x C])^T * (*inv)
__global__ void tscalebf_k(const float* __restrict__ in, us* __restrict__ out,
                           const float* __restrict__ inv, int R, int C) {
  __shared__ float tile[32][33];
  float s = *inv;
  int c0 = blockIdx.x * 32, r0 = blockIdx.y * 32;
  int tx = threadIdx.x, ty = threadIdx.y;
#pragma unroll
  for (int j = 0; j < 4; ++j)
    tile[ty + 8 * j][tx] = in[(size_t)(r0 + ty + 8 * j) * C + c0 + tx];
  __syncthreads();
#pragma unroll
  for (int j = 0; j < 4; ++j)
    out[(size_t)(c0 + ty + 8 * j) * R + r0 + tx] = f2bf(tile[tx][ty + 8 * j] * s);
}

// batched bf16 transpose: in[2][1024][2048] -> out[2][2048][1024]
__global__ void tbf_k(const us* __restrict__ in, us* __restrict__ out) {
  __shared__ us tile[32][33];
  size_t bo = (size_t)blockIdx.z * 2097152;
  int c0 = blockIdx.x * 32, r0 = blockIdx.y * 32;
  int tx = threadIdx.x, ty = threadIdx.y;
#pragma unroll
  for (int j = 0; j < 4; ++j)
    tile[ty + 8 * j][tx] = in[bo + (size_t)(r0 + ty + 8 * j) * 2048 + c0 + tx];
  __syncthreads();
#pragma unroll
  for (int j = 0; j < 4; ++j)
    out[bo + (size_t)(c0 + ty + 8 * j) * 1024 + r0 + tx] = tile[tx][ty + 8 * j];
}

// W0(f32 1024x2048) = om*W0 + lr*bf(X); also W0bT(us 2048x1024) = W0^T
__global__ void wupd0_k(float* __restrict__ W0, const us* __restrict__ X,
                        us* __restrict__ W0bT, const float* __restrict__ cp, int c) {
  __shared__ float tl[32][33];
  float lr = cp[c * 3 + 0], om = 1.0f - cp[c * 3 + 2];
  int c0 = blockIdx.x * 32, r0 = blockIdx.y * 32;  // c0 over H, r0 over P
  int tx = threadIdx.x, ty = threadIdx.y;
#pragma unroll
  for (int j = 0; j < 4; ++j) {
    int r = r0 + ty + 8 * j, h = c0 + tx;
    size_t idx = (size_t)r * 2048 + h;
    float v = om * W0[idx] + lr * bf2f(X[idx]);
    W0[idx] = v;
    tl[ty + 8 * j][tx] = v;
  }
  __syncthreads();
#pragma unroll
  for (int j = 0; j < 4; ++j)
    W0bT[(size_t)(c0 + ty + 8 * j) * 1024 + r0 + tx] = f2bf(tl[tx][ty + 8 * j]);
}

// W1(f32 2048x1024): W1[h][p] = om*W1[h][p] + lr*bf(X2[p][h]); X2 = 1024x2048
// also W1b(us 2048x1024) and W1bT(us 1024x2048)
__global__ void wupd1_k(float* __restrict__ W1, const us* __restrict__ X2,
                        us* __restrict__ W1b, us* __restrict__ W1bT,
                        const float* __restrict__ cp, int c) {
  __shared__ float tX[32][33];
  __shared__ float t2[32][33];
  float lr = cp[c * 3 + 0], om = 1.0f - cp[c * 3 + 2];
  int h0 = blockIdx.x * 32, p0 = blockIdx.y * 32;
  int tx = threadIdx.x, ty = threadIdx.y;
#pragma unroll
  for (int j = 0; j < 4; ++j)
    tX[ty + 8 * j][tx] = bf2f(X2[(size_t)(p0 + ty + 8 * j) * 2048 + h0 + tx]);
  __syncthreads();
#pragma unroll
  for (int j = 0; j < 4; ++j) {
    int h = h0 + ty + 8 * j, p = p0 + tx;
    size_t idx = (size_t)h * 1024 + p;
    float v = om * W1[idx] + lr * tX[tx][ty + 8 * j];
    W1[idx] = v;
    W1b[idx] = f2bf(v);
    t2[tx][ty + 8 * j] = v;  // [p_local][h_local]
  }
  __syncthreads();
#pragma unroll
  for (int j = 0; j < 4; ++j)
    W1bT[(size_t)(p0 + ty + 8 * j) * 2048 + h0 + tx] = f2bf(t2[ty + 8 * j][tx]);
}

// ---------------- host ----------------

extern "C" void kernel_launch(void* const* d_in, const int* in_sizes, int n_in,
                              void* d_out, int out_size, void* d_ws, size_t ws_size,
                              hipStream_t stream) {
  const float* x = (const float*)d_in[0];
  const float* Wk = (const float*)d_in[1];
  const float* Wv = (const float*)d_in[2];
  const float* Wq = (const float*)d_in[3];
  const float* Wout = (const float*)d_in[4];
  const float* w_lr = (const float*)d_in[5];
  const float* b_lr = (const float*)d_in[6];
  const float* w_mom = (const float*)d_in[7];
  const float* b_mom = (const float*)d_in[8];
  const float* w_dec = (const float*)d_in[9];
  const float* b_dec = (const float*)d_in[10];
  const float* w_gate = (const float*)d_in[11];
  const float* b_gate = (const float*)d_in[12];
  const float* Wmem0 = (const float*)d_in[13];
  const float* Wmem1 = (const float*)d_in[14];
  const float* Wmemout = (const float*)d_in[15];
  const float* Wvexp = (const float*)d_in[16];
  float* out = (float*)d_out;
  (void)n_in; (void)in_sizes; (void)out_size;

  const long F = 1048576;
  const long BIG = 2097152;           // 1024*2048
  const long SB2 = 2097152, SB1 = 1048576;
  float* ws = (float*)d_ws;
  if (ws_size < (size_t)25043464 * sizeof(float)) return;

  us* kp_b   = (us*)ws;               // [0,1F) : 2048x1024 bf16 chunk-major
  us* qp_b   = (us*)(ws + F);         // [1,2)
  float* vexp = ws + 2 * F;           // [2,4) : 2048x1024 f32 chunk-major
  float* W0  = ws + 4 * F;            // [4,6) : 1024x2048 f32
  float* W1  = ws + 6 * F;            // [6,8) : 2048x1024 f32
  float* S0  = ws + 8 * F;            // [8,10)
  float* S1  = ws + 10 * F;           // [10,12)
  us* XA     = (us*)(ws + 12 * F);    // [12,14) : [2][1024][2048] bf16 | xb (prologue)
  us* XB     = (us*)(ws + 14 * F);    // [14,16) : same | Wkb/Wqb/Wvb (prologue)
  us* XT     = (us*)(ws + 16 * F);    // [16,18) : [2][2048][1024] | vlin+WvexpT (prologue)
  us* Ab     = (us*)(ws + 18 * F);    // [18,19) : [2][1024][1024] | Woutb (final)
  float* SCR = ws + 19 * F;           // [19,20) : Bb | lin | chunk scratch
  us* W0bT   = (us*)(ws + 20 * F);    // [20,21) : 2048x1024 bf16
  us* W1bT   = (us*)(ws + 21 * F);    // [21,22) : 1024x2048 bf16
  us* W1b    = (us*)(ws + 22 * F);    // [22,23) : 2048x1024 bf16
  us* WmoT   = (us*)(ws + 23 * F);    // [23,23.25) : 512x1024 bf16
  us* retrv  = (us*)(ws + 23 * F + 262144);   // 2048x512 bf16 chunk-major (0.5F)
  float* smal = ws + 23 * F + 262144 + 524288;
  float* og   = smal;
  float* lrv  = og + 2048;
  float* momv = lrv + 2048;
  float* decv = momv + 2048;
  float* cpb  = decv + 2048;          // 32*3
  float* w0inv = cpb + 128;
  float* w1inv = w0inv + 64;
  float* parts = w1inv + 64;          // 256
  float* inv0  = parts + 256;
  float* inv1  = inv0 + 1;

  // prologue aliases
  us* xb   = XA;                       // 2048x2048 bf16
  us* Wkb  = XB;                       // 512x2048
  us* Wqb  = XB + 1048576;
  us* Wvb  = XB + 2097152;
  us* vlin = XT;                       // 2048x512 bf16
  us* WvexpT = XT + 1048576;           // 1024x512 bf16
  us* Woutb = Ab;                      // 2048x512 bf16 (after chunk loop)
  float* lin = SCR;                    // 2048x512 f32 (prologue)
  us* Bb = (us*)SCR;                   // [2][1024][1024] bf16 (NS loop)
  // per-chunk scratch (within SCR, dead before NS loop)
  us* hab   = (us*)SCR;                // 128x2048 bf16  (131072 floats)
  float* gp = SCR + 131072;            // 64x2048 f32    (131072)
  us* pr    = (us*)(SCR + 262144);     // 128x1024 bf16  (65536)
  float* dh = SCR + 327680;            // 64x2048 f32    (131072)
  us* dhT   = (us*)(SCR + 458752);     // 2048x64 bf16   (65536)
  us* rbwT  = (us*)(SCR + 524288);     // 1024x64 bf16   (32768)

  const float NSa = 3.4445f, NSb = -4.7750f, NSc = 2.0315f;

  // ---- init masters + bf16 weight copies ----
  hipMemcpyAsync(W0, Wmem0, (size_t)BIG * 4, hipMemcpyDeviceToDevice, stream);
  hipMemcpyAsync(W1, Wmem1, (size_t)BIG * 4, hipMemcpyDeviceToDevice, stream);
  hipMemsetAsync(S0, 0, (size_t)BIG * 4, stream);
  hipMemsetAsync(S1, 0, (size_t)BIG * 4, stream);
  hipLaunchKernelGGL(tconv_k, dim3(64, 32), dim3(32, 8), 0, stream, Wmem0, W0bT, 1024, 2048);
  hipLaunchKernelGGL(conv_k, dim3(1024), dim3(256), 0, stream, Wmem1, W1b, (int)BIG);
  hipLaunchKernelGGL(tconv_k, dim3(32, 64), dim3(32, 8), 0, stream, Wmem1, W1bT, 2048, 1024);
  hipLaunchKernelGGL(tconv_k, dim3(16, 32), dim3(32, 8), 0, stream, Wmemout, WmoT, 1024, 512);
  hipLaunchKernelGGL(tconv_k, dim3(32, 16), dim3(32, 8), 0, stream, Wvexp, WvexpT, 512, 1024);
  hipLaunchKernelGGL(conv_k, dim3(2048), dim3(256), 0, stream, x, xb, 2048 * 2048);
  hipLaunchKernelGGL(conv_k, dim3(512), dim3(256), 0, stream, Wk, Wkb, 512 * 2048);
  hipLaunchKernelGGL(conv_k, dim3(512), dim3(256), 0, stream, Wq, Wqb, 512 * 2048);
  hipLaunchKernelGGL(conv_k, dim3(512), dim3(256), 0, stream, Wv, Wvb, 512 * 2048);

  // ---- projections + poly (MFMA) ----
  mg<7>(stream, xb, nullptr, Wkb, lin, nullptr, nullptr, nullptr, nullptr, nullptr, 0,
        2048, 512, 2048, 2048, 2048, 512, 0, 0.f, 0.f, 0, 0, 0, 0, 1);
  hipLaunchKernelGGL(polynorm2_k, dim3(2048), dim3(256), 0, stream, lin, kp_b);
  mg<7>(stream, xb, nullptr, Wqb, lin, nullptr, nullptr, nullptr, nullptr, nullptr, 0,
        2048, 512, 2048, 2048, 2048, 512, 0, 0.f, 0.f, 0, 0, 0, 0, 1);
  hipLaunchKernelGGL(polynorm2_k, dim3(2048), dim3(256), 0, stream, lin, qp_b);
  mg<5>(stream, xb, nullptr, Wvb, vlin, nullptr, nullptr, nullptr, nullptr, nullptr, 0,
        2048, 512, 2048, 2048, 2048, 512, 0, 0.f, 0.f, 0, 0, 0, 0, 1);
  mg<17>(stream, vlin, nullptr, WvexpT, vexp, nullptr, nullptr, nullptr, nullptr, nullptr, 0,
         2048, 1024, 512, 512, 512, 1024, 0, 0.f, 0.f, 0, 0, 0, 0, 1);

  // ---- gates + chunk means ----
  hipLaunchKernelGGL(gates_k, dim3(2048), dim3(256), 0, stream, x,
                     w_lr, b_lr, w_mom, b_mom, w_dec, b_dec, w_gate, b_gate,
                     lrv, momv, decv, og);
  hipLaunchKernelGGL(chunk_means_k, dim3(32), dim3(64), 0, stream, lrv, momv, decv, cpb);

  // ---- sequential chunk scan ----
  for (int c = 0; c < 32; ++c) {
    const us* kp_c = kp_b + (size_t)c * 64 * 1024;
    const us* qp_c = qp_b + (size_t)c * 64 * 1024;
    const float* vexp_c = vexp + (size_t)c * 64 * 1024;
    // G1: [qc;kc]@W0 -> hab (gelu), gp (gelu' for grad rows)
    mg<8, 0, 1>(stream, qp_c, kp_c, W0bT, hab, gp, nullptr, nullptr, nullptr, nullptr, 0,
                128, 2048, 1024, 1024, 1024, 2048, 0, 0.f, 0.f, 0, 0, 0, 0, 1);
    // G2: hab@W1 -> pr (rows<64 pred_retr; rows>=64 resid 2*(pred - vexp))
    mg<9>(stream, hab, nullptr, W1bT, pr, nullptr, vexp_c, nullptr, nullptr, nullptr, 0,
          128, 1024, 2048, 2048, 2048, 1024, 1024, 0.f, 0.f, 0, 0, 0, 0, 1);
    // G3: pred@Wmemout -> retrv (chunk-major)
    mg<5>(stream, pr, nullptr, WmoT, retrv + (size_t)c * 64 * 512, nullptr, nullptr,
          nullptr, nullptr, nullptr, 0,
          64, 512, 1024, 1024, 1024, 512, 0, 0.f, 0.f, 0, 0, 0, 0, 1);
    // G4: r@W1^T * gelu' -> dh (f32)
    mg<13>(stream, pr + 64 * 1024, nullptr, W1b, dh, nullptr, gp, nullptr, nullptr, nullptr, 0,
           64, 2048, 1024, 1024, 1024, 2048, 2048, 0.f, 0.f, 0, 0, 0, 0, 1);
    hipLaunchKernelGGL(sampnorm2_k, dim3(64), dim3(256), 0, stream,
                       kp_b, dh, hab, pr, w0inv, w1inv, c);
    hipLaunchKernelGGL((wtrans_k<1>), dim3(64, 2), dim3(32, 8), 0, stream, dh, w0inv, dhT, 2048, 2048);
    hipLaunchKernelGGL((wtrans_k<0>), dim3(32, 2), dim3(32, 8), 0, stream, pr + 64 * 1024, w1inv,
                       rbwT, 1024, 1024);
    // G5: S0 = mom*S0 - lr*(kc^T dh_w)
    mg<14, 1>(stream, kp_c, nullptr, dhT, S0, nullptr, nullptr, nullptr, nullptr, cpb, c,
              1024, 2048, 64, 1024, 64, 2048, 0, 0.f, 0.f, 0, 0, 0, 0, 1);
    // G6: S1 = mom*S1 - lr*(a^T r_w)
    mg<14, 1>(stream, hab + 64 * 2048, nullptr, rbwT, S1, nullptr, nullptr, nullptr, nullptr, cpb, c,
              2048, 1024, 64, 2048, 64, 1024, 0, 0.f, 0.f, 0, 0, 0, 0, 1);

    // ---- batched NS5: batch0 = S0 (1024x2048), batch1 = S1^T ----
    hipLaunchKernelGGL(frob_k, dim3(256), dim3(256), 0, stream, S0, (int)BIG, parts);
    hipLaunchKernelGGL(frob_fin_k, dim3(1), dim3(256), 0, stream, parts, inv0);
    hipLaunchKernelGGL(frob_k, dim3(256), dim3(256), 0, stream, S1, (int)BIG, parts);
    hipLaunchKernelGGL(frob_fin_k, dim3(1), dim3(256), 0, stream, parts, inv1);
    hipLaunchKernelGGL(scalebf_k, dim3(1024), dim3(256), 0, stream, S0, XA, inv0, (int)BIG);
    hipLaunchKernelGGL(tscalebf_k, dim3(64, 32), dim3(32, 8), 0, stream, S0, XT, inv0, 1024, 2048);
    hipLaunchKernelGGL(scalebf_k, dim3(1024), dim3(256), 0, stream, S1, XT + SB2, inv1, (int)BIG);
    hipLaunchKernelGGL(tscalebf_k, dim3(32, 64), dim3(32, 8), 0, stream, S1, XA + SB2, inv1, 2048, 1024);

    us* Xc = XA;
    us* Xn = XB;
    for (int it = 0; it < 5; ++it) {
      // Ab = Xc @ Xc^T
      mg<5>(stream, Xc, nullptr, Xc, Ab, nullptr, nullptr, nullptr, nullptr, nullptr, 0,
            1024, 1024, 2048, 2048, 2048, 1024, 0, 0.f, 0.f, SB2, SB2, SB1, 0, 2);
      // Bb = NSc*(Ab@Ab) + NSb*Ab
      mg<6>(stream, Ab, nullptr, Ab, Bb, nullptr, Ab, nullptr, nullptr, nullptr, 0,
            1024, 1024, 1024, 1024, 1024, 1024, 1024, NSc, NSb, SB1, SB1, SB1, SB1, 2);
      // Xn = Bb@Xc + NSa*Xc
      mg<6>(stream, Bb, nullptr, XT, Xn, nullptr, Xc, nullptr, nullptr, nullptr, 0,
            1024, 2048, 1024, 1024, 1024, 2048, 2048, 1.0f, NSa, SB1, SB2, SB2, SB2, 2);
      if (it < 4)
        hipLaunchKernelGGL(tbf_k, dim3(64, 32, 2), dim3(32, 8), 0, stream, Xn, XT);
      us* tmp = Xc; Xc = Xn; Xn = tmp;
    }
    hipLaunchKernelGGL(wupd0_k, dim3(64, 32), dim3(32, 8), 0, stream, W0, Xc, W0bT, cpb, c);
    hipLaunchKernelGGL(wupd1_k, dim3(64, 32), dim3(32, 8), 0, stream, W1, Xc + SB2, W1b, W1bT, cpb, c);
  }

  // ---- final: out = x + (retrv_tok @ Wout^T) * og ----
  hipLaunchKernelGGL(conv_k, dim3(1024), dim3(256), 0, stream, Wout, Woutb, 2048 * 512);
  mg<15, 0, 0, 1>(stream, retrv, nullptr, Woutb, out, nullptr, nullptr, x, og, nullptr, 0,
                  2048, 2048, 512, 512, 512, 2048, 0, 0.f, 0.f, 0, 0, 0, 0, 1);
}

// Round 6
// 17373.087 us; speedup vs baseline: 5.3015x; 1.1652x over previous
//
#include <hip/hip_runtime.h>

// ---------------------------------------------------------------------------
// DeepMemoryLevel (ATLAS-style). B=2 S=1024 D=2048 M=512 P=1024 H=2048
// CHUNK=32 NC=32, tokens N=2048.
// Round 6: software-pipelined 1-wave 64x64 MFMA GEMM (reg prefetch +
// double-buffered LDS, 1 barrier/K-step); merged frob and scale+transpose
// kernels. W0/W1 f32 masters with bf16(+T) copies refreshed on update.
// ---------------------------------------------------------------------------

typedef unsigned short us;
typedef __attribute__((ext_vector_type(8))) short s16x8;
typedef __attribute__((ext_vector_type(8))) unsigned short u16x8;
typedef __attribute__((ext_vector_type(4))) float f32x4;

#define MKP 72

__device__ __forceinline__ float gelu_f(float x) {
  return 0.5f * x * (1.0f + erff(x * 0.70710678118654752f));
}
__device__ __forceinline__ float gelu_grad_f(float x) {
  float cdf = 0.5f * (1.0f + erff(x * 0.70710678118654752f));
  float pdf = 0.3989422804014327f * expf(-0.5f * x * x);
  return cdf + x * pdf;
}
__device__ __forceinline__ float sigmoid_f(float x) { return 1.0f / (1.0f + expf(-x)); }

__device__ __forceinline__ us f2bf(float f) {
  union { float f; unsigned u; } v; v.f = f;
  unsigned r = (v.u + 0x7FFFu + ((v.u >> 16) & 1u)) >> 16;
  return (us)r;
}
__device__ __forceinline__ float bf2f(us h) {
  union { unsigned u; float f; } v; v.u = ((unsigned)h) << 16;
  return v.f;
}
// token-major index n -> chunk-major row
__device__ __forceinline__ int cm_map(int n) {
  return ((n & 1023) >> 5) * 64 + (n >> 10) * 32 + (n & 31);
}

__device__ __forceinline__ float block_reduce_sum(float v, float* red) {
  int t = threadIdx.x;
  red[t] = v; __syncthreads();
  for (int s = blockDim.x >> 1; s > 0; s >>= 1) {
    if (t < s) red[t] += red[t + s];
    __syncthreads();
  }
  float r = red[0];
  __syncthreads();
  return r;
}

// ---------------- 1-wave 64x64 bf16 MFMA GEMM (pipelined) ----------------
// C[M,N] = A @ Bsrc^T, Bsrc row-major N x K (ldb).
// TA=0: A row-major M x K (lda). TA=1: A row-major K x M (lda = M-stride).
// DUAL: block rows [64,128) read from A2 (row-64). AG: global A row = cm_map.
// EPI: 5  C us = acc
//      6  C us = c1*acc + c2*bf(E_us[m,n])           (batched NS)
//      7  C f32 = acc
//      8  C us = gelu(acc); if m0>=64: C2 f32[(m-64),n] = gelu'(acc)
//      9  C us: m0<64 -> acc ; else -> 2*(acc - E_f32[(m-64),n])
//      13 C f32 = acc * E_f32[m,n]
//      14 C f32 = cp[3ci+1]*C_old - cp[3ci]*acc
//      15 C f32 = FX[m,n] + acc*OG[m]
//      17 C f32, row scattered to cm_map(m)
template<int EPI, int TA, int DUAL, int AG>
__global__ __launch_bounds__(64)
void mg_k(const us* __restrict__ Aq, const us* __restrict__ A2,
          const us* __restrict__ Bq, void* __restrict__ Cq,
          void* __restrict__ C2, const void* __restrict__ Eq,
          const float* __restrict__ FX, const float* __restrict__ OG,
          const float* __restrict__ cp, int cidx,
          int M, int N, int K, int lda, int ldb, int ldc, int lde,
          float c1, float c2, long sA, long sB, long sC, long sE) {
  __shared__ __align__(16) us As[2 * 64 * MKP];
  __shared__ __align__(16) us Bs[2 * 64 * MKP];
  const int bz = blockIdx.z;
  const us* A = Aq + (size_t)bz * sA;
  const us* B = Bq + (size_t)bz * sB;
  const int t = threadIdx.x;
  const int m0 = blockIdx.y * 64, n0 = blockIdx.x * 64;
  if constexpr (DUAL) { if (m0 >= 64) A = A2; }
  const int mA0 = DUAL ? (m0 & 63) : m0;
  const int l15 = t & 15, l4 = t >> 4;

  f32x4 acc[4][4];
#pragma unroll
  for (int i = 0; i < 4; ++i)
#pragma unroll
    for (int j = 0; j < 4; ++j) acc[i][j] = (f32x4){0.f, 0.f, 0.f, 0.f};

  const int srw = t >> 3;          // 0..7 base row / k
  const int sck = (t & 7) * 8;     // 0..56 col chunk

  u16x8 ra[8], rb[8];
  auto LDA = [&](int k0) {
#pragma unroll
    for (int p = 0; p < 8; ++p) {
      if constexpr (TA == 0) {
        int row = srw + p * 8;
        int srow;
        if constexpr (AG) srow = cm_map(m0 + row); else srow = mA0 + row;
        ra[p] = *(const u16x8*)(A + (size_t)srow * lda + k0 + sck);
      } else {
        ra[p] = *(const u16x8*)(A + (size_t)(k0 + srw + p * 8) * lda + mA0 + sck);
      }
    }
  };
  auto LDB = [&](int k0) {
#pragma unroll
    for (int p = 0; p < 8; ++p)
      rb[p] = *(const u16x8*)(B + (size_t)(n0 + srw + p * 8) * ldb + k0 + sck);
  };

  LDA(0); LDB(0);
  int cur = 0;
  for (int k0 = 0; k0 < K; k0 += 64) {
    us* Ac = As + cur * (64 * MKP);
    us* Bc = Bs + cur * (64 * MKP);
    // stage current regs -> LDS
    if constexpr (TA == 0) {
#pragma unroll
      for (int p = 0; p < 8; ++p)
        *(u16x8*)&Ac[(srw + p * 8) * MKP + sck] = ra[p];
    } else {
#pragma unroll
      for (int p = 0; p < 8; ++p) {
        int kk = srw + p * 8;
#pragma unroll
        for (int j = 0; j < 8; ++j) Ac[(sck + j) * MKP + kk] = ra[p][j];
      }
    }
#pragma unroll
    for (int p = 0; p < 8; ++p)
      *(u16x8*)&Bc[(srw + p * 8) * MKP + sck] = rb[p];
    __syncthreads();
    // prefetch next K-step (flies under the MFMA section below)
    if (k0 + 64 < K) { LDA(k0 + 64); LDB(k0 + 64); }
#pragma unroll
    for (int ks = 0; ks < 2; ++ks) {
      s16x8 af[4], bf[4];
#pragma unroll
      for (int mi = 0; mi < 4; ++mi)
        af[mi] = *(const s16x8*)&Ac[(mi * 16 + l15) * MKP + ks * 32 + l4 * 8];
#pragma unroll
      for (int ni = 0; ni < 4; ++ni)
        bf[ni] = *(const s16x8*)&Bc[(ni * 16 + l15) * MKP + ks * 32 + l4 * 8];
#pragma unroll
      for (int mi = 0; mi < 4; ++mi)
#pragma unroll
        for (int ni = 0; ni < 4; ++ni)
          acc[mi][ni] = __builtin_amdgcn_mfma_f32_16x16x32_bf16(af[mi], bf[ni], acc[mi][ni], 0, 0, 0);
    }
    cur ^= 1;
  }

#pragma unroll
  for (int mi = 0; mi < 4; ++mi) {
#pragma unroll
    for (int i = 0; i < 4; ++i) {
      int grow = m0 + mi * 16 + l4 * 4 + i;
#pragma unroll
      for (int ni = 0; ni < 4; ++ni) {
        int col = n0 + ni * 16 + l15;
        float v = acc[mi][ni][i];
        if constexpr (EPI == 5) {
          ((us*)Cq + bz * sC)[(size_t)grow * ldc + col] = f2bf(v);
        } else if constexpr (EPI == 6) {
          const us* E = (const us*)Eq + bz * sE;
          ((us*)Cq + bz * sC)[(size_t)grow * ldc + col] =
              f2bf(c1 * v + c2 * bf2f(E[(size_t)grow * lde + col]));
        } else if constexpr (EPI == 7) {
          ((float*)Cq)[(size_t)grow * ldc + col] = v;
        } else if constexpr (EPI == 8) {
          ((us*)Cq)[(size_t)grow * ldc + col] = f2bf(gelu_f(v));
          if (m0 >= 64)
            ((float*)C2)[(size_t)(grow - 64) * ldc + col] = gelu_grad_f(v);
        } else if constexpr (EPI == 9) {
          if (m0 < 64)
            ((us*)Cq)[(size_t)grow * ldc + col] = f2bf(v);
          else
            ((us*)Cq)[(size_t)grow * ldc + col] =
                f2bf(2.0f * (v - ((const float*)Eq)[(size_t)(grow - 64) * lde + col]));
        } else if constexpr (EPI == 13) {
          ((float*)Cq)[(size_t)grow * ldc + col] =
              v * ((const float*)Eq)[(size_t)grow * lde + col];
        } else if constexpr (EPI == 14) {
          float* C = (float*)Cq;
          float old = C[(size_t)grow * ldc + col];
          C[(size_t)grow * ldc + col] = cp[cidx * 3 + 1] * old - cp[cidx * 3 + 0] * v;
        } else if constexpr (EPI == 15) {
          ((float*)Cq)[(size_t)grow * ldc + col] =
              FX[(size_t)grow * ldc + col] + v * OG[grow];
        } else if constexpr (EPI == 17) {
          int crow = cm_map(grow);
          ((float*)Cq)[(size_t)crow * ldc + col] = v;
        }
      }
    }
  }
}

template<int EPI, int TA = 0, int DUAL = 0, int AG = 0>
static void mg(hipStream_t st, const us* A, const us* A2, const us* B,
               void* C, void* C2, const void* E,
               const float* FX, const float* OG, const float* cp, int cidx,
               int M, int N, int K, int lda, int ldb, int ldc, int lde,
               float c1, float c2, long sA, long sB, long sC, long sE, int batch) {
  dim3 g(N / 64, M / 64, batch), b(64);
  hipLaunchKernelGGL((mg_k<EPI, TA, DUAL, AG>), g, b, 0, st, A, A2, B, C, C2, E,
                     FX, OG, cp, cidx, M, N, K, lda, ldb, ldc, lde, c1, c2, sA, sB, sC, sE);
}

// ---------------- conversions ----------------

__global__ __launch_bounds__(256) void conv_k(const float* __restrict__ in,
                                              us* __restrict__ out, int n) {
  for (int i = blockIdx.x * 256 + threadIdx.x; i < n; i += gridDim.x * 256)
    out[i] = f2bf(in[i]);
}

// out_bf16[C x R] = (in_f32[R x C])^T
__global__ void tconv_k(const float* __restrict__ in, us* __restrict__ out, int R, int C) {
  __shared__ float tile[32][33];
  int c0 = blockIdx.x * 32, r0 = blockIdx.y * 32;
  int tx = threadIdx.x, ty = threadIdx.y;
#pragma unroll
  for (int j = 0; j < 4; ++j)
    tile[ty + 8 * j][tx] = in[(size_t)(r0 + ty + 8 * j) * C + c0 + tx];
  __syncthreads();
#pragma unroll
  for (int j = 0; j < 4; ++j)
    out[(size_t)(c0 + ty + 8 * j) * R + r0 + tx] = f2bf(tile[tx][ty + 8 * j]);
}

// ---------------- elementwise / reductions ----------------

// per-token normalize + poly, writing bf16 chunk-major
__global__ __launch_bounds__(256) void polynorm2_k(const float* __restrict__ lin,
                                                   us* __restrict__ outp) {
  __shared__ float red[256];
  int n = blockIdx.x, t = threadIdx.x;
  int rowp = cm_map(n);
  float s = 0.f;
  for (int f = t; f < 512; f += 256) { float v = lin[(size_t)n * 512 + f]; s += v * v; }
  float tot = block_reduce_sum(s, red);
  float sc = 1.0f / fmaxf(sqrtf(tot), 1e-12f);
  const float is2 = 0.70710678118654752f;
  for (int f = t; f < 512; f += 256) {
    float v = lin[(size_t)n * 512 + f] * sc;
    outp[(size_t)rowp * 1024 + f] = f2bf(v * is2);
    outp[(size_t)rowp * 1024 + 512 + f] = f2bf(v * v * is2);
  }
}

__global__ __launch_bounds__(256) void gates_k(const float* __restrict__ x,
    const float* __restrict__ wlr, const float* __restrict__ blr,
    const float* __restrict__ wmom, const float* __restrict__ bmom,
    const float* __restrict__ wdec, const float* __restrict__ bdec,
    const float* __restrict__ wgate, const float* __restrict__ bgate,
    float* __restrict__ lrv, float* __restrict__ momv,
    float* __restrict__ decv, float* __restrict__ og) {
  __shared__ float red[256];
  int n = blockIdx.x, t = threadIdx.x;
  float s0 = 0.f, s1 = 0.f, s2 = 0.f, s3 = 0.f;
  for (int d = t; d < 2048; d += 256) {
    float xv = x[(size_t)n * 2048 + d];
    s0 += xv * wlr[d]; s1 += xv * wmom[d]; s2 += xv * wdec[d]; s3 += xv * wgate[d];
  }
  float r0 = block_reduce_sum(s0, red);
  float r1 = block_reduce_sum(s1, red);
  float r2 = block_reduce_sum(s2, red);
  float r3 = block_reduce_sum(s3, red);
  if (t == 0) {
    lrv[n] = sigmoid_f(r0 + blr[0]);
    momv[n] = sigmoid_f(r1 + bmom[0]);
    decv[n] = sigmoid_f(r2 + bdec[0]);
    og[n] = sigmoid_f(r3 + bgate[0]);
  }
}

__global__ void chunk_means_k(const float* __restrict__ lrv, const float* __restrict__ momv,
                              const float* __restrict__ decv, float* __restrict__ cp) {
  int c = blockIdx.x, t = threadIdx.x;  // 64 threads
  int n = ((t >> 5) << 10) + c * 32 + (t & 31);
  float a = lrv[n], b = momv[n], d = decv[n];
  for (int off = 32; off > 0; off >>= 1) {
    a += __shfl_down(a, off);
    b += __shfl_down(b, off);
    d += __shfl_down(d, off);
  }
  if (t == 0) {
    cp[c * 3 + 0] = a * (1.f / 64.f);
    cp[c * 3 + 1] = b * (1.f / 64.f);
    cp[c * 3 + 2] = d * (1.f / 64.f);
  }
}

// per-sample clip weights (chunk-major inputs)
__global__ __launch_bounds__(256) void sampnorm2_k(const us* __restrict__ kp_b,
                                                   const float* __restrict__ dh,
                                                   const us* __restrict__ hab,
                                                   const us* __restrict__ pr,
                                                   float* __restrict__ w0inv,
                                                   float* __restrict__ w1inv, int c) {
  __shared__ float red[256];
  int i = blockIdx.x, t = threadIdx.x;
  int row = c * 64 + i;
  float sk = 0.f, sr = 0.f, sdh = 0.f, sa = 0.f;
  for (int p = t; p < 1024; p += 256) {
    float v = bf2f(kp_b[(size_t)row * 1024 + p]); sk += v * v;
    v = bf2f(pr[(size_t)(64 + i) * 1024 + p]); sr += v * v;
  }
  for (int h = t; h < 2048; h += 256) {
    float v = dh[(size_t)i * 2048 + h]; sdh += v * v;
    v = bf2f(hab[(size_t)(64 + i) * 2048 + h]); sa += v * v;
  }
  float tk = block_reduce_sum(sk, red);
  float tdh = block_reduce_sum(sdh, red);
  float ta = block_reduce_sum(sa, red);
  float tr = block_reduce_sum(sr, red);
  if (t == 0) {
    float n0 = fmaxf(sqrtf(tk) * sqrtf(tdh), 1e-8f);
    w0inv[i] = 1.0f / (64.0f * fmaxf(n0 * 0.1f, 1.0f));
    float n1 = fmaxf(sqrtf(ta) * sqrtf(tr), 1e-8f);
    w1inv[i] = 1.0f / (64.0f * fmaxf(n1 * 0.1f, 1.0f));
  }
}

// out_bf16[C x 64] = (in[64 x C] * w[row])^T ; INF32 selects input dtype
template<int INF32>
__global__ void wtrans_k(const void* __restrict__ in, const float* __restrict__ w,
                         us* __restrict__ out, int C, int ldin) {
  __shared__ float tile[32][33];
  int c0 = blockIdx.x * 32, r0 = blockIdx.y * 32;
  int tx = threadIdx.x, ty = threadIdx.y;
#pragma unroll
  for (int j = 0; j < 4; ++j) {
    int r = r0 + ty + 8 * j, cc = c0 + tx;
    float v;
    if constexpr (INF32) v = ((const float*)in)[(size_t)r * ldin + cc];
    else v = bf2f(((const us*)in)[(size_t)r * ldin + cc]);
    tile[ty + 8 * j][tx] = v * w[r];
  }
  __syncthreads();
#pragma unroll
  for (int j = 0; j < 4; ++j)
    out[(size_t)(c0 + ty + 8 * j) * 64 + r0 + tx] = f2bf(tile[tx][ty + 8 * j]);
}

// batched frobenius: blockIdx.z selects S0/S1
__global__ __launch_bounds__(256) void frob2_k(const float* __restrict__ s0,
                                               const float* __restrict__ s1, int n,
                                               float* __restrict__ parts) {
  __shared__ float red[256];
  const float* s = blockIdx.z ? s1 : s0;
  float acc = 0.f;
  for (int i = blockIdx.x * 256 + threadIdx.x; i < n; i += gridDim.x * 256) {
    float v = s[i]; acc += v * v;
  }
  float r = block_reduce_sum(acc, red);
  if (threadIdx.x == 0) parts[blockIdx.z * 256 + blockIdx.x] = r;
}

__global__ __launch_bounds__(256) void frob_fin2_k(const float* __restrict__ parts,
                                                   float* __restrict__ inv) {
  __shared__ float red[256];
  float r = block_reduce_sum(parts[blockIdx.x * 256 + threadIdx.x], red);
  if (threadIdx.x == 0) inv[blockIdx.x] = 1.0f / (sqrtf(r) + 1e-7f);
}

// reads in f32 [R x C]; writes outS = bf(in*s) [R x C] and outT = bf(in*s)^T [C x R]
__global__ void scale_dual_k(const float* __restrict__ in, us* __restrict__ outS,
                             us* __restrict__ outT, const float* __restrict__ inv,
                             int R, int C) {
  __shared__ float tile[32][33];
  float s = *inv;
  int c0 = blockIdx.x * 32, r0 = blockIdx.y * 32;
  int tx = threadIdx.x, ty = threadIdx.y;
#pragma unroll
  for (int j = 0; j < 4; ++j) {
    float v = in[(size_t)(r0 + ty + 8 * j) * C + c0 + tx];
    tile[ty + 8 * j][tx] = v;
    outS[(size_t)(r0 + ty + 8 * j) * C + c0 + tx] = f2bf(v * s);
  }
  __syncthreads();
#pragma unroll
  for (int j = 0; j < 4; ++j)
    outT[(size_t)(c0 + ty + 8 * j) * R + r0 + tx] = f2bf(tile[tx][ty + 8 * j] * s);
}

// batched bf16 transpose: in[2][1024][2048] -> out[2][2048][1024]
__global__ void tbf_k(const us* __restrict__ in, us* __restrict__ out) {
  __shared__ us tile[32][33];
  size_t bo = (size_t)blockIdx.z * 2097152;
  int c0 = blockIdx.x * 32, r0 = blockIdx.y * 32;
  int tx = threadIdx.x, ty = threadIdx.y;
#pragma unroll
  for (int j = 0; j < 4; ++j)
    tile[ty + 8 * j][tx] = in[bo + (size_t)(r0 + ty + 8 * j) * 2048 + c0 + tx];
  __syncthreads();
#pragma unroll
  for (int j = 0; j < 4; ++j)
    out[bo + (size_t)(c0 + ty + 8 * j) * 1024 + r0 + tx] = tile[tx][ty + 8 * j];
}

// W0(f32 1024x2048) = om*W0 + lr*bf(X); also W0bT(us 2048x1024) = W0^T
__global__ void wupd0_k(float* __restrict__ W0, const us* __restrict__ X,
                        us* __restrict__ W0bT, const float* __restrict__ cp, int c) {
  __shared__ float tl[32][33];
  float lr = cp[c * 3 + 0], om = 1.0f - cp[c * 3 + 2];
  int c0 = blockIdx.x * 32, r0 = blockIdx.y * 32;  // c0 over H, r0 over P
  int tx = threadIdx.x, ty = threadIdx.y;
#pragma unroll
  for (int j = 0; j < 4; ++j) {
    int r = r0 + ty + 8 * j, h = c0 + tx;
    size_t idx = (size_t)r * 2048 + h;
    float v = om * W0[idx] + lr * bf2f(X[idx]);
    W0[idx] = v;
    tl[ty + 8 * j][tx] = v;
  }
  __syncthreads();
#pragma unroll
  for (int j = 0; j < 4; ++j)
    W0bT[(size_t)(c0 + ty + 8 * j) * 1024 + r0 + tx] = f2bf(tl[tx][ty + 8 * j]);
}

// W1(f32 2048x1024): W1[h][p] = om*W1[h][p] + lr*bf(X2[p][h]); X2 = 1024x2048
// also W1b(us 2048x1024) and W1bT(us 1024x2048)
__global__ void wupd1_k(float* __restrict__ W1, const us* __restrict__ X2,
                        us* __restrict__ W1b, us* __restrict__ W1bT,
                        const float* __restrict__ cp, int c) {
  __shared__ float tX[32][33];
  __shared__ float t2[32][33];
  float lr = cp[c * 3 + 0], om = 1.0f - cp[c * 3 + 2];
  int h0 = blockIdx.x * 32, p0 = blockIdx.y * 32;
  int tx = threadIdx.x, ty = threadIdx.y;
#pragma unroll
  for (int j = 0; j < 4; ++j)
    tX[ty + 8 * j][tx] = bf2f(X2[(size_t)(p0 + ty + 8 * j) * 2048 + h0 + tx]);
  __syncthreads();
#pragma unroll
  for (int j = 0; j < 4; ++j) {
    int h = h0 + ty + 8 * j, p = p0 + tx;
    size_t idx = (size_t)h * 1024 + p;
    float v = om * W1[idx] + lr * tX[tx][ty + 8 * j];
    W1[idx] = v;
    W1b[idx] = f2bf(v);
    t2[tx][ty + 8 * j] = v;  // [p_local][h_local]
  }
  __syncthreads();
#pragma unroll
  for (int j = 0; j < 4; ++j)
    W1bT[(size_t)(p0 + ty + 8 * j) * 2048 + h0 + tx] = f2bf(t2[ty + 8 * j][tx]);
}

// ---------------- host ----------------

extern "C" void kernel_launch(void* const* d_in, const int* in_sizes, int n_in,
                              void* d_out, int out_size, void* d_ws, size_t ws_size,
                              hipStream_t stream) {
  const float* x = (const float*)d_in[0];
  const float* Wk = (const float*)d_in[1];
  const float* Wv = (const float*)d_in[2];
  const float* Wq = (const float*)d_in[3];
  const float* Wout = (const float*)d_in[4];
  const float* w_lr = (const float*)d_in[5];
  const float* b_lr = (const float*)d_in[6];
  const float* w_mom = (const float*)d_in[7];
  const float* b_mom = (const float*)d_in[8];
  const float* w_dec = (const float*)d_in[9];
  const float* b_dec = (const float*)d_in[10];
  const float* w_gate = (const float*)d_in[11];
  const float* b_gate = (const float*)d_in[12];
  const float* Wmem0 = (const float*)d_in[13];
  const float* Wmem1 = (const float*)d_in[14];
  const float* Wmemout = (const float*)d_in[15];
  const float* Wvexp = (const float*)d_in[16];
  float* out = (float*)d_out;
  (void)n_in; (void)in_sizes; (void)out_size;

  const long F = 1048576;
  const long BIG = 2097152;           // 1024*2048
  const long SB2 = 2097152, SB1 = 1048576;
  float* ws = (float*)d_ws;
  if (ws_size < (size_t)25043464 * sizeof(float)) return;

  us* kp_b   = (us*)ws;               // [0,1F) : 2048x1024 bf16 chunk-major
  us* qp_b   = (us*)(ws + F);         // [1,2)
  float* vexp = ws + 2 * F;           // [2,4) : 2048x1024 f32 chunk-major
  float* W0  = ws + 4 * F;            // [4,6) : 1024x2048 f32
  float* W1  = ws + 6 * F;            // [6,8) : 2048x1024 f32
  float* S0  = ws + 8 * F;            // [8,10)
  float* S1  = ws + 10 * F;           // [10,12)
  us* XA     = (us*)(ws + 12 * F);    // [12,14) : [2][1024][2048] bf16 | xb (prologue)
  us* XB     = (us*)(ws + 14 * F);    // [14,16) : same | Wkb/Wqb/Wvb (prologue)
  us* XT     = (us*)(ws + 16 * F);    // [16,18) : [2][2048][1024] | vlin+WvexpT (prologue)
  us* Ab     = (us*)(ws + 18 * F);    // [18,19) : [2][1024][1024] | Woutb (final)
  float* SCR = ws + 19 * F;           // [19,20) : Bb | lin | chunk scratch
  us* W0bT   = (us*)(ws + 20 * F);    // [20,21) : 2048x1024 bf16
  us* W1bT   = (us*)(ws + 21 * F);    // [21,22) : 1024x2048 bf16
  us* W1b    = (us*)(ws + 22 * F);    // [22,23) : 2048x1024 bf16
  us* WmoT   = (us*)(ws + 23 * F);    // [23,23.25) : 512x1024 bf16
  us* retrv  = (us*)(ws + 23 * F + 262144);   // 2048x512 bf16 chunk-major (0.5F)
  float* smal = ws + 23 * F + 262144 + 524288;
  float* og   = smal;
  float* lrv  = og + 2048;
  float* momv = lrv + 2048;
  float* decv = momv + 2048;
  float* cpb  = decv + 2048;          // 32*3
  float* w0inv = cpb + 128;
  float* w1inv = w0inv + 64;
  float* parts = w1inv + 64;          // 512 (2 x 256)
  float* inv01 = parts + 512;         // inv[0], inv[1]

  // prologue aliases
  us* xb   = XA;                       // 2048x2048 bf16
  us* Wkb  = XB;                       // 512x2048
  us* Wqb  = XB + 1048576;
  us* Wvb  = XB + 2097152;
  us* vlin = XT;                       // 2048x512 bf16
  us* WvexpT = XT + 1048576;           // 1024x512 bf16
  us* Woutb = Ab;                      // 2048x512 bf16 (final)
  float* lin = SCR;                    // 2048x512 f32 (prologue)
  us* Bb = (us*)SCR;                   // [2][1024][1024] bf16 (NS loop)
  // per-chunk scratch (within SCR, dead before NS loop)
  us* hab   = (us*)SCR;                // 128x2048 bf16  (131072 floats)
  float* gp = SCR + 131072;            // 64x2048 f32    (131072)
  us* pr    = (us*)(SCR + 262144);     // 128x1024 bf16  (65536)
  float* dh = SCR + 327680;            // 64x2048 f32    (131072)
  us* dhT   = (us*)(SCR + 458752);     // 2048x64 bf16   (65536)
  us* rbwT  = (us*)(SCR + 524288);     // 1024x64 bf16   (32768)

  const float NSa = 3.4445f, NSb = -4.7750f, NSc = 2.0315f;

  // ---- init masters + bf16 weight copies ----
  hipMemcpyAsync(W0, Wmem0, (size_t)BIG * 4, hipMemcpyDeviceToDevice, stream);
  hipMemcpyAsync(W1, Wmem1, (size_t)BIG * 4, hipMemcpyDeviceToDevice, stream);
  hipMemsetAsync(S0, 0, (size_t)BIG * 4, stream);
  hipMemsetAsync(S1, 0, (size_t)BIG * 4, stream);
  hipLaunchKernelGGL(tconv_k, dim3(64, 32), dim3(32, 8), 0, stream, Wmem0, W0bT, 1024, 2048);
  hipLaunchKernelGGL(conv_k, dim3(1024), dim3(256), 0, stream, Wmem1, W1b, (int)BIG);
  hipLaunchKernelGGL(tconv_k, dim3(32, 64), dim3(32, 8), 0, stream, Wmem1, W1bT, 2048, 1024);
  hipLaunchKernelGGL(tconv_k, dim3(16, 32), dim3(32, 8), 0, stream, Wmemout, WmoT, 1024, 512);
  hipLaunchKernelGGL(tconv_k, dim3(32, 16), dim3(32, 8), 0, stream, Wvexp, WvexpT, 512, 1024);
  hipLaunchKernelGGL(conv_k, dim3(2048), dim3(256), 0, stream, x, xb, 2048 * 2048);
  hipLaunchKernelGGL(conv_k, dim3(512), dim3(256), 0, stream, Wk, Wkb, 512 * 2048);
  hipLaunchKernelGGL(conv_k, dim3(512), dim3(256), 0, stream, Wq, Wqb, 512 * 2048);
  hipLaunchKernelGGL(conv_k, dim3(512), dim3(256), 0, stream, Wv, Wvb, 512 * 2048);

  // ---- projections + poly (MFMA) ----
  mg<7>(stream, xb, nullptr, Wkb, lin, nullptr, nullptr, nullptr, nullptr, nullptr, 0,
        2048, 512, 2048, 2048, 2048, 512, 0, 0.f, 0.f, 0, 0, 0, 0, 1);
  hipLaunchKernelGGL(polynorm2_k, dim3(2048), dim3(256), 0, stream, lin, kp_b);
  mg<7>(stream, xb, nullptr, Wqb, lin, nullptr, nullptr, nullptr, nullptr, nullptr, 0,
        2048, 512, 2048, 2048, 2048, 512, 0, 0.f, 0.f, 0, 0, 0, 0, 1);
  hipLaunchKernelGGL(polynorm2_k, dim3(2048), dim3(256), 0, stream, lin, qp_b);
  mg<5>(stream, xb, nullptr, Wvb, vlin, nullptr, nullptr, nullptr, nullptr, nullptr, 0,
        2048, 512, 2048, 2048, 2048, 512, 0, 0.f, 0.f, 0, 0, 0, 0, 1);
  mg<17>(stream, vlin, nullptr, WvexpT, vexp, nullptr, nullptr, nullptr, nullptr, nullptr, 0,
         2048, 1024, 512, 512, 512, 1024, 0, 0.f, 0.f, 0, 0, 0, 0, 1);

  // ---- gates + chunk means ----
  hipLaunchKernelGGL(gates_k, dim3(2048), dim3(256), 0, stream, x,
                     w_lr, b_lr, w_mom, b_mom, w_dec, b_dec, w_gate, b_gate,
                     lrv, momv, decv, og);
  hipLaunchKernelGGL(chunk_means_k, dim3(32), dim3(64), 0, stream, lrv, momv, decv, cpb);

  // ---- sequential chunk scan ----
  for (int c = 0; c < 32; ++c) {
    const us* kp_c = kp_b + (size_t)c * 64 * 1024;
    const us* qp_c = qp_b + (size_t)c * 64 * 1024;
    const float* vexp_c = vexp + (size_t)c * 64 * 1024;
    // G1: [qc;kc]@W0 -> hab (gelu), gp (gelu' for grad rows)
    mg<8, 0, 1>(stream, qp_c, kp_c, W0bT, hab, gp, nullptr, nullptr, nullptr, nullptr, 0,
                128, 2048, 1024, 1024, 1024, 2048, 0, 0.f, 0.f, 0, 0, 0, 0, 1);
    // G2: hab@W1 -> pr (rows<64 pred_retr; rows>=64 resid 2*(pred - vexp))
    mg<9>(stream, hab, nullptr, W1bT, pr, nullptr, vexp_c, nullptr, nullptr, nullptr, 0,
          128, 1024, 2048, 2048, 2048, 1024, 1024, 0.f, 0.f, 0, 0, 0, 0, 1);
    // G3: pred@Wmemout -> retrv (chunk-major)
    mg<5>(stream, pr, nullptr, WmoT, retrv + (size_t)c * 64 * 512, nullptr, nullptr,
          nullptr, nullptr, nullptr, 0,
          64, 512, 1024, 1024, 1024, 512, 0, 0.f, 0.f, 0, 0, 0, 0, 1);
    // G4: r@W1^T * gelu' -> dh (f32)
    mg<13>(stream, pr + 64 * 1024, nullptr, W1b, dh, nullptr, gp, nullptr, nullptr, nullptr, 0,
           64, 2048, 1024, 1024, 1024, 2048, 2048, 0.f, 0.f, 0, 0, 0, 0, 1);
    hipLaunchKernelGGL(sampnorm2_k, dim3(64), dim3(256), 0, stream,
                       kp_b, dh, hab, pr, w0inv, w1inv, c);
    hipLaunchKernelGGL((wtrans_k<1>), dim3(64, 2), dim3(32, 8), 0, stream, dh, w0inv, dhT, 2048, 2048);
    hipLaunchKernelGGL((wtrans_k<0>), dim3(32, 2), dim3(32, 8), 0, stream, pr + 64 * 1024, w1inv,
                       rbwT, 1024, 1024);
    // G5: S0 = mom*S0 - lr*(kc^T dh_w)
    mg<14, 1>(stream, kp_c, nullptr, dhT, S0, nullptr, nullptr, nullptr, nullptr, cpb, c,
              1024, 2048, 64, 1024, 64, 2048, 0, 0.f, 0.f, 0, 0, 0, 0, 1);
    // G6: S1 = mom*S1 - lr*(a^T r_w)
    mg<14, 1>(stream, hab + 64 * 2048, nullptr, rbwT, S1, nullptr, nullptr, nullptr, nullptr, cpb, c,
              2048, 1024, 64, 2048, 64, 1024, 0, 0.f, 0.f, 0, 0, 0, 0, 1);

    // ---- batched NS5: batch0 = S0 (1024x2048), batch1 = S1^T ----
    hipLaunchKernelGGL(frob2_k, dim3(256, 1, 2), dim3(256), 0, stream, S0, S1, (int)BIG, parts);
    hipLaunchKernelGGL(frob_fin2_k, dim3(2), dim3(256), 0, stream, parts, inv01);
    hipLaunchKernelGGL(scale_dual_k, dim3(64, 32), dim3(32, 8), 0, stream,
                       S0, XA, XT, inv01, 1024, 2048);
    hipLaunchKernelGGL(scale_dual_k, dim3(32, 64), dim3(32, 8), 0, stream,
                       S1, XT + SB2, XA + SB2, inv01 + 1, 2048, 1024);

    us* Xc = XA;
    us* Xn = XB;
    for (int it = 0; it < 5; ++it) {
      // Ab = Xc @ Xc^T
      mg<5>(stream, Xc, nullptr, Xc, Ab, nullptr, nullptr, nullptr, nullptr, nullptr, 0,
            1024, 1024, 2048, 2048, 2048, 1024, 0, 0.f, 0.f, SB2, SB2, SB1, 0, 2);
      // Bb = NSc*(Ab@Ab) + NSb*Ab
      mg<6>(stream, Ab, nullptr, Ab, Bb, nullptr, Ab, nullptr, nullptr, nullptr, 0,
            1024, 1024, 1024, 1024, 1024, 1024, 1024, NSc, NSb, SB1, SB1, SB1, SB1, 2);
      // Xn = Bb@Xc + NSa*Xc
      mg<6>(stream, Bb, nullptr, XT, Xn, nullptr, Xc, nullptr, nullptr, nullptr, 0,
            1024, 2048, 1024, 1024, 1024, 2048, 2048, 1.0f, NSa, SB1, SB2, SB2, SB2, 2);
      if (it < 4)
        hipLaunchKernelGGL(tbf_k, dim3(64, 32, 2), dim3(32, 8), 0, stream, Xn, XT);
      us* tmp = Xc; Xc = Xn; Xn = tmp;
    }
    hipLaunchKernelGGL(wupd0_k, dim3(64, 32), dim3(32, 8), 0, stream, W0, Xc, W0bT, cpb, c);
    hipLaunchKernelGGL(wupd1_k, dim3(64, 32), dim3(32, 8), 0, stream, W1, Xc + SB2, W1b, W1bT, cpb, c);
  }

  // ---- final: out = x + (retrv_tok @ Wout^T) * og ----
  hipLaunchKernelGGL(conv_k, dim3(1024), dim3(256), 0, stream, Wout, Woutb, 2048 * 512);
  mg<15, 0, 0, 1>(stream, retrv, nullptr, Woutb, out, nullptr, nullptr, x, og, nullptr, 0,
                  2048, 2048, 512, 512, 512, 2048, 0, 0.f, 0.f, 0, 0, 0, 0, 1);
}

// Round 7
// 16889.391 us; speedup vs baseline: 5.4533x; 1.0286x over previous
//
#include <hip/hip_runtime.h>

// ---------------------------------------------------------------------------
// DeepMemoryLevel (ATLAS-style). B=2 S=1024 D=2048 M=512 P=1024 H=2048
// CHUNK=32 NC=32, tokens N=2048.
// Round 7: barrier-free 1-wave 64x64 MFMA GEMM. Single-wave workgroups need
// no __syncthreads (per-wave DS ops are in-order); compiler emits counted
// vmcnt/lgkmcnt waits. Single LDS buffer (18.4KB -> 8 blocks/CU) + register
// prefetch of next K-tile under the MFMA phase.
// ---------------------------------------------------------------------------

typedef unsigned short us;
typedef __attribute__((ext_vector_type(8))) short s16x8;
typedef __attribute__((ext_vector_type(8))) unsigned short u16x8;
typedef __attribute__((ext_vector_type(4))) float f32x4;

#define MKP 72

__device__ __forceinline__ float gelu_f(float x) {
  return 0.5f * x * (1.0f + erff(x * 0.70710678118654752f));
}
__device__ __forceinline__ float gelu_grad_f(float x) {
  float cdf = 0.5f * (1.0f + erff(x * 0.70710678118654752f));
  float pdf = 0.3989422804014327f * expf(-0.5f * x * x);
  return cdf + x * pdf;
}
__device__ __forceinline__ float sigmoid_f(float x) { return 1.0f / (1.0f + expf(-x)); }

__device__ __forceinline__ us f2bf(float f) {
  union { float f; unsigned u; } v; v.f = f;
  unsigned r = (v.u + 0x7FFFu + ((v.u >> 16) & 1u)) >> 16;
  return (us)r;
}
__device__ __forceinline__ float bf2f(us h) {
  union { unsigned u; float f; } v; v.u = ((unsigned)h) << 16;
  return v.f;
}
// token-major index n -> chunk-major row
__device__ __forceinline__ int cm_map(int n) {
  return ((n & 1023) >> 5) * 64 + (n >> 10) * 32 + (n & 31);
}

__device__ __forceinline__ float block_reduce_sum(float v, float* red) {
  int t = threadIdx.x;
  red[t] = v; __syncthreads();
  for (int s = blockDim.x >> 1; s > 0; s >>= 1) {
    if (t < s) red[t] += red[t + s];
    __syncthreads();
  }
  float r = red[0];
  __syncthreads();
  return r;
}

// ---------------- 1-wave 64x64 bf16 MFMA GEMM (barrier-free pipeline) -------
// C[M,N] = A @ Bsrc^T, Bsrc row-major N x K (ldb).
// TA=0: A row-major M x K (lda). TA=1: A row-major K x M (lda = M-stride).
// DUAL: block rows [64,128) read from A2 (row-64). AG: global A row = cm_map.
// EPI: 5  C us = acc
//      6  C us = c1*acc + c2*bf(E_us[m,n])           (batched NS)
//      7  C f32 = acc
//      8  C us = gelu(acc); if m0>=64: C2 f32[(m-64),n] = gelu'(acc)
//      9  C us: m0<64 -> acc ; else -> 2*(acc - E_f32[(m-64),n])
//      13 C f32 = acc * E_f32[m,n]
//      14 C f32 = cp[3ci+1]*C_old - cp[3ci]*acc
//      15 C f32 = FX[m,n] + acc*OG[m]
//      17 C f32, row scattered to cm_map(m)
template<int EPI, int TA, int DUAL, int AG>
__global__ __launch_bounds__(64)
void mg_k(const us* __restrict__ Aq, const us* __restrict__ A2,
          const us* __restrict__ Bq, void* __restrict__ Cq,
          void* __restrict__ C2, const void* __restrict__ Eq,
          const float* __restrict__ FX, const float* __restrict__ OG,
          const float* __restrict__ cp, int cidx,
          int M, int N, int K, int lda, int ldb, int ldc, int lde,
          float c1, float c2, long sA, long sB, long sC, long sE) {
  __shared__ __align__(16) us As[64 * MKP];
  __shared__ __align__(16) us Bs[64 * MKP];
  const int bz = blockIdx.z;
  const us* A = Aq + (size_t)bz * sA;
  const us* B = Bq + (size_t)bz * sB;
  const int t = threadIdx.x;
  const int m0 = blockIdx.y * 64, n0 = blockIdx.x * 64;
  if constexpr (DUAL) { if (m0 >= 64) A = A2; }
  const int mA0 = DUAL ? (m0 & 63) : m0;
  const int l15 = t & 15, l4 = t >> 4;

  f32x4 acc[4][4];
#pragma unroll
  for (int i = 0; i < 4; ++i)
#pragma unroll
    for (int j = 0; j < 4; ++j) acc[i][j] = (f32x4){0.f, 0.f, 0.f, 0.f};

  const int srw = t >> 3;          // 0..7 base row / k
  const int sck = (t & 7) * 8;     // 0..56 col chunk

  u16x8 ra[8], rb[8];
  auto LDA = [&](int k0) {
#pragma unroll
    for (int p = 0; p < 8; ++p) {
      if constexpr (TA == 0) {
        int row = srw + p * 8;
        int srow;
        if constexpr (AG) srow = cm_map(m0 + row); else srow = mA0 + row;
        ra[p] = *(const u16x8*)(A + (size_t)srow * lda + k0 + sck);
      } else {
        ra[p] = *(const u16x8*)(A + (size_t)(k0 + srw + p * 8) * lda + mA0 + sck);
      }
    }
  };
  auto LDB = [&](int k0) {
#pragma unroll
    for (int p = 0; p < 8; ++p)
      rb[p] = *(const u16x8*)(B + (size_t)(n0 + srw + p * 8) * ldb + k0 + sck);
  };

  LDA(0); LDB(0);
  for (int k0 = 0; k0 < K; k0 += 64) {
    // stage current regs -> LDS (compiler inserts counted vmcnt waits;
    // per-wave DS in-order execution makes this safe w/o barriers: these
    // writes cannot pass the previous iteration's ds_reads)
    if constexpr (TA == 0) {
#pragma unroll
      for (int p = 0; p < 8; ++p)
        *(u16x8*)&As[(srw + p * 8) * MKP + sck] = ra[p];
    } else {
#pragma unroll
      for (int p = 0; p < 8; ++p) {
        int kk = srw + p * 8;
#pragma unroll
        for (int j = 0; j < 8; ++j) As[(sck + j) * MKP + kk] = ra[p][j];
      }
    }
#pragma unroll
    for (int p = 0; p < 8; ++p)
      *(u16x8*)&Bs[(srw + p * 8) * MKP + sck] = rb[p];
    // prefetch next K-step (flies under the MFMA section below)
    if (k0 + 64 < K) { LDA(k0 + 64); LDB(k0 + 64); }
#pragma unroll
    for (int ks = 0; ks < 2; ++ks) {
      s16x8 af[4], bf[4];
#pragma unroll
      for (int mi = 0; mi < 4; ++mi)
        af[mi] = *(const s16x8*)&As[(mi * 16 + l15) * MKP + ks * 32 + l4 * 8];
#pragma unroll
      for (int ni = 0; ni < 4; ++ni)
        bf[ni] = *(const s16x8*)&Bs[(ni * 16 + l15) * MKP + ks * 32 + l4 * 8];
#pragma unroll
      for (int mi = 0; mi < 4; ++mi)
#pragma unroll
        for (int ni = 0; ni < 4; ++ni)
          acc[mi][ni] = __builtin_amdgcn_mfma_f32_16x16x32_bf16(af[mi], bf[ni], acc[mi][ni], 0, 0, 0);
    }
  }

#pragma unroll
  for (int mi = 0; mi < 4; ++mi) {
#pragma unroll
    for (int i = 0; i < 4; ++i) {
      int grow = m0 + mi * 16 + l4 * 4 + i;
#pragma unroll
      for (int ni = 0; ni < 4; ++ni) {
        int col = n0 + ni * 16 + l15;
        float v = acc[mi][ni][i];
        if constexpr (EPI == 5) {
          ((us*)Cq + bz * sC)[(size_t)grow * ldc + col] = f2bf(v);
        } else if constexpr (EPI == 6) {
          const us* E = (const us*)Eq + bz * sE;
          ((us*)Cq + bz * sC)[(size_t)grow * ldc + col] =
              f2bf(c1 * v + c2 * bf2f(E[(size_t)grow * lde + col]));
        } else if constexpr (EPI == 7) {
          ((float*)Cq)[(size_t)grow * ldc + col] = v;
        } else if constexpr (EPI == 8) {
          ((us*)Cq)[(size_t)grow * ldc + col] = f2bf(gelu_f(v));
          if (m0 >= 64)
            ((float*)C2)[(size_t)(grow - 64) * ldc + col] = gelu_grad_f(v);
        } else if constexpr (EPI == 9) {
          if (m0 < 64)
            ((us*)Cq)[(size_t)grow * ldc + col] = f2bf(v);
          else
            ((us*)Cq)[(size_t)grow * ldc + col] =
                f2bf(2.0f * (v - ((const float*)Eq)[(size_t)(grow - 64) * lde + col]));
        } else if constexpr (EPI == 13) {
          ((float*)Cq)[(size_t)grow * ldc + col] =
              v * ((const float*)Eq)[(size_t)grow * lde + col];
        } else if constexpr (EPI == 14) {
          float* C = (float*)Cq;
          float old = C[(size_t)grow * ldc + col];
          C[(size_t)grow * ldc + col] = cp[cidx * 3 + 1] * old - cp[cidx * 3 + 0] * v;
        } else if constexpr (EPI == 15) {
          ((float*)Cq)[(size_t)grow * ldc + col] =
              FX[(size_t)grow * ldc + col] + v * OG[grow];
        } else if constexpr (EPI == 17) {
          int crow = cm_map(grow);
          ((float*)Cq)[(size_t)crow * ldc + col] = v;
        }
      }
    }
  }
}

template<int EPI, int TA = 0, int DUAL = 0, int AG = 0>
static void mg(hipStream_t st, const us* A, const us* A2, const us* B,
               void* C, void* C2, const void* E,
               const float* FX, const float* OG, const float* cp, int cidx,
               int M, int N, int K, int lda, int ldb, int ldc, int lde,
               float c1, float c2, long sA, long sB, long sC, long sE, int batch) {
  dim3 g(N / 64, M / 64, batch), b(64);
  hipLaunchKernelGGL((mg_k<EPI, TA, DUAL, AG>), g, b, 0, st, A, A2, B, C, C2, E,
                     FX, OG, cp, cidx, M, N, K, lda, ldb, ldc, lde, c1, c2, sA, sB, sC, sE);
}

// ---------------- conversions ----------------

__global__ __launch_bounds__(256) void conv_k(const float* __restrict__ in,
                                              us* __restrict__ out, int n) {
  for (int i = blockIdx.x * 256 + threadIdx.x; i < n; i += gridDim.x * 256)
    out[i] = f2bf(in[i]);
}

// out_bf16[C x R] = (in_f32[R x C])^T
__global__ void tconv_k(const float* __restrict__ in, us* __restrict__ out, int R, int C) {
  __shared__ float tile[32][33];
  int c0 = blockIdx.x * 32, r0 = blockIdx.y * 32;
  int tx = threadIdx.x, ty = threadIdx.y;
#pragma unroll
  for (int j = 0; j < 4; ++j)
    tile[ty + 8 * j][tx] = in[(size_t)(r0 + ty + 8 * j) * C + c0 + tx];
  __syncthreads();
#pragma unroll
  for (int j = 0; j < 4; ++j)
    out[(size_t)(c0 + ty + 8 * j) * R + r0 + tx] = f2bf(tile[tx][ty + 8 * j]);
}

// ---------------- elementwise / reductions ----------------

// per-token normalize + poly, writing bf16 chunk-major
__global__ __launch_bounds__(256) void polynorm2_k(const float* __restrict__ lin,
                                                   us* __restrict__ outp) {
  __shared__ float red[256];
  int n = blockIdx.x, t = threadIdx.x;
  int rowp = cm_map(n);
  float s = 0.f;
  for (int f = t; f < 512; f += 256) { float v = lin[(size_t)n * 512 + f]; s += v * v; }
  float tot = block_reduce_sum(s, red);
  float sc = 1.0f / fmaxf(sqrtf(tot), 1e-12f);
  const float is2 = 0.70710678118654752f;
  for (int f = t; f < 512; f += 256) {
    float v = lin[(size_t)n * 512 + f] * sc;
    outp[(size_t)rowp * 1024 + f] = f2bf(v * is2);
    outp[(size_t)rowp * 1024 + 512 + f] = f2bf(v * v * is2);
  }
}

__global__ __launch_bounds__(256) void gates_k(const float* __restrict__ x,
    const float* __restrict__ wlr, const float* __restrict__ blr,
    const float* __restrict__ wmom, const float* __restrict__ bmom,
    const float* __restrict__ wdec, const float* __restrict__ bdec,
    const float* __restrict__ wgate, const float* __restrict__ bgate,
    float* __restrict__ lrv, float* __restrict__ momv,
    float* __restrict__ decv, float* __restrict__ og) {
  __shared__ float red[256];
  int n = blockIdx.x, t = threadIdx.x;
  float s0 = 0.f, s1 = 0.f, s2 = 0.f, s3 = 0.f;
  for (int d = t; d < 2048; d += 256) {
    float xv = x[(size_t)n * 2048 + d];
    s0 += xv * wlr[d]; s1 += xv * wmom[d]; s2 += xv * wdec[d]; s3 += xv * wgate[d];
  }
  float r0 = block_reduce_sum(s0, red);
  float r1 = block_reduce_sum(s1, red);
  float r2 = block_reduce_sum(s2, red);
  float r3 = block_reduce_sum(s3, red);
  if (t == 0) {
    lrv[n] = sigmoid_f(r0 + blr[0]);
    momv[n] = sigmoid_f(r1 + bmom[0]);
    decv[n] = sigmoid_f(r2 + bdec[0]);
    og[n] = sigmoid_f(r3 + bgate[0]);
  }
}

__global__ void chunk_means_k(const float* __restrict__ lrv, const float* __restrict__ momv,
                              const float* __restrict__ decv, float* __restrict__ cp) {
  int c = blockIdx.x, t = threadIdx.x;  // 64 threads
  int n = ((t >> 5) << 10) + c * 32 + (t & 31);
  float a = lrv[n], b = momv[n], d = decv[n];
  for (int off = 32; off > 0; off >>= 1) {
    a += __shfl_down(a, off);
    b += __shfl_down(b, off);
    d += __shfl_down(d, off);
  }
  if (t == 0) {
    cp[c * 3 + 0] = a * (1.f / 64.f);
    cp[c * 3 + 1] = b * (1.f / 64.f);
    cp[c * 3 + 2] = d * (1.f / 64.f);
  }
}

// per-sample clip weights (chunk-major inputs)
__global__ __launch_bounds__(256) void sampnorm2_k(const us* __restrict__ kp_b,
                                                   const float* __restrict__ dh,
                                                   const us* __restrict__ hab,
                                                   const us* __restrict__ pr,
                                                   float* __restrict__ w0inv,
                                                   float* __restrict__ w1inv, int c) {
  __shared__ float red[256];
  int i = blockIdx.x, t = threadIdx.x;
  int row = c * 64 + i;
  float sk = 0.f, sr = 0.f, sdh = 0.f, sa = 0.f;
  for (int p = t; p < 1024; p += 256) {
    float v = bf2f(kp_b[(size_t)row * 1024 + p]); sk += v * v;
    v = bf2f(pr[(size_t)(64 + i) * 1024 + p]); sr += v * v;
  }
  for (int h = t; h < 2048; h += 256) {
    float v = dh[(size_t)i * 2048 + h]; sdh += v * v;
    v = bf2f(hab[(size_t)(64 + i) * 2048 + h]); sa += v * v;
  }
  float tk = block_reduce_sum(sk, red);
  float tdh = block_reduce_sum(sdh, red);
  float ta = block_reduce_sum(sa, red);
  float tr = block_reduce_sum(sr, red);
  if (t == 0) {
    float n0 = fmaxf(sqrtf(tk) * sqrtf(tdh), 1e-8f);
    w0inv[i] = 1.0f / (64.0f * fmaxf(n0 * 0.1f, 1.0f));
    float n1 = fmaxf(sqrtf(ta) * sqrtf(tr), 1e-8f);
    w1inv[i] = 1.0f / (64.0f * fmaxf(n1 * 0.1f, 1.0f));
  }
}

// out_bf16[C x 64] = (in[64 x C] * w[row])^T ; INF32 selects input dtype
template<int INF32>
__global__ void wtrans_k(const void* __restrict__ in, const float* __restrict__ w,
                         us* __restrict__ out, int C, int ldin) {
  __shared__ float tile[32][33];
  int c0 = blockIdx.x * 32, r0 = blockIdx.y * 32;
  int tx = threadIdx.x, ty = threadIdx.y;
#pragma unroll
  for (int j = 0; j < 4; ++j) {
    int r = r0 + ty + 8 * j, cc = c0 + tx;
    float v;
    if constexpr (INF32) v = ((const float*)in)[(size_t)r * ldin + cc];
    else v = bf2f(((const us*)in)[(size_t)r * ldin + cc]);
    tile[ty + 8 * j][tx] = v * w[r];
  }
  __syncthreads();
#pragma unroll
  for (int j = 0; j < 4; ++j)
    out[(size_t)(c0 + ty + 8 * j) * 64 + r0 + tx] = f2bf(tile[tx][ty + 8 * j]);
}

// batched frobenius: blockIdx.z selects S0/S1
__global__ __launch_bounds__(256) void frob2_k(const float* __restrict__ s0,
                                               const float* __restrict__ s1, int n,
                                               float* __restrict__ parts) {
  __shared__ float red[256];
  const float* s = blockIdx.z ? s1 : s0;
  float acc = 0.f;
  for (int i = blockIdx.x * 256 + threadIdx.x; i < n; i += gridDim.x * 256) {
    float v = s[i]; acc += v * v;
  }
  float r = block_reduce_sum(acc, red);
  if (threadIdx.x == 0) parts[blockIdx.z * 256 + blockIdx.x] = r;
}

__global__ __launch_bounds__(256) void frob_fin2_k(const float* __restrict__ parts,
                                                   float* __restrict__ inv) {
  __shared__ float red[256];
  float r = block_reduce_sum(parts[blockIdx.x * 256 + threadIdx.x], red);
  if (threadIdx.x == 0) inv[blockIdx.x] = 1.0f / (sqrtf(r) + 1e-7f);
}

// reads in f32 [R x C]; writes outS = bf(in*s) [R x C] and outT = bf(in*s)^T [C x R]
__global__ void scale_dual_k(const float* __restrict__ in, us* __restrict__ outS,
                             us* __restrict__ outT, const float* __restrict__ inv,
                             int R, int C) {
  __shared__ float tile[32][33];
  float s = *inv;
  int c0 = blockIdx.x * 32, r0 = blockIdx.y * 32;
  int tx = threadIdx.x, ty = threadIdx.y;
#pragma unroll
  for (int j = 0; j < 4; ++j) {
    float v = in[(size_t)(r0 + ty + 8 * j) * C + c0 + tx];
    tile[ty + 8 * j][tx] = v;
    outS[(size_t)(r0 + ty + 8 * j) * C + c0 + tx] = f2bf(v * s);
  }
  __syncthreads();
#pragma unroll
  for (int j = 0; j < 4; ++j)
    outT[(size_t)(c0 + ty + 8 * j) * R + r0 + tx] = f2bf(tile[tx][ty + 8 * j] * s);
}

// batched bf16 transpose: in[2][1024][2048] -> out[2][2048][1024]
__global__ void tbf_k(const us* __restrict__ in, us* __restrict__ out) {
  __shared__ us tile[32][33];
  size_t bo = (size_t)blockIdx.z * 2097152;
  int c0 = blockIdx.x * 32, r0 = blockIdx.y * 32;
  int tx = threadIdx.x, ty = threadIdx.y;
#pragma unroll
  for (int j = 0; j < 4; ++j)
    tile[ty + 8 * j][tx] = in[bo + (size_t)(r0 + ty + 8 * j) * 2048 + c0 + tx];
  __syncthreads();
#pragma unroll
  for (int j = 0; j < 4; ++j)
    out[bo + (size_t)(c0 + ty + 8 * j) * 1024 + r0 + tx] = tile[tx][ty + 8 * j];
}

// W0(f32 1024x2048) = om*W0 + lr*bf(X); also W0bT(us 2048x1024) = W0^T
__global__ void wupd0_k(float* __restrict__ W0, const us* __restrict__ X,
                        us* __restrict__ W0bT, const float* __restrict__ cp, int c) {
  __shared__ float tl[32][33];
  float lr = cp[c * 3 + 0], om = 1.0f - cp[c * 3 + 2];
  int c0 = blockIdx.x * 32, r0 = blockIdx.y * 32;  // c0 over H, r0 over P
  int tx = threadIdx.x, ty = threadIdx.y;
#pragma unroll
  for (int j = 0; j < 4; ++j) {
    int r = r0 + ty + 8 * j, h = c0 + tx;
    size_t idx = (size_t)r * 2048 + h;
    float v = om * W0[idx] + lr * bf2f(X[idx]);
    W0[idx] = v;
    tl[ty + 8 * j][tx] = v;
  }
  __syncthreads();
#pragma unroll
  for (int j = 0; j < 4; ++j)
    W0bT[(size_t)(c0 + ty + 8 * j) * 1024 + r0 + tx] = f2bf(tl[tx][ty + 8 * j]);
}

// W1(f32 2048x1024): W1[h][p] = om*W1[h][p] + lr*bf(X2[p][h]); X2 = 1024x2048
// also W1b(us 2048x1024) and W1bT(us 1024x2048)
__global__ void wupd1_k(float* __restrict__ W1, const us* __restrict__ X2,
                        us* __restrict__ W1b, us* __restrict__ W1bT,
                        const float* __restrict__ cp, int c) {
  __shared__ float tX[32][33];
  __shared__ float t2[32][33];
  float lr = cp[c * 3 + 0], om = 1.0f - cp[c * 3 + 2];
  int h0 = blockIdx.x * 32, p0 = blockIdx.y * 32;
  int tx = threadIdx.x, ty = threadIdx.y;
#pragma unroll
  for (int j = 0; j < 4; ++j)
    tX[ty + 8 * j][tx] = bf2f(X2[(size_t)(p0 + ty + 8 * j) * 2048 + h0 + tx]);
  __syncthreads();
#pragma unroll
  for (int j = 0; j < 4; ++j) {
    int h = h0 + ty + 8 * j, p = p0 + tx;
    size_t idx = (size_t)h * 1024 + p;
    float v = om * W1[idx] + lr * tX[tx][ty + 8 * j];
    W1[idx] = v;
    W1b[idx] = f2bf(v);
    t2[tx][ty + 8 * j] = v;  // [p_local][h_local]
  }
  __syncthreads();
#pragma unroll
  for (int j = 0; j < 4; ++j)
    W1bT[(size_t)(p0 + ty + 8 * j) * 2048 + h0 + tx] = f2bf(t2[ty + 8 * j][tx]);
}

// ---------------- host ----------------

extern "C" void kernel_launch(void* const* d_in, const int* in_sizes, int n_in,
                              void* d_out, int out_size, void* d_ws, size_t ws_size,
                              hipStream_t stream) {
  const float* x = (const float*)d_in[0];
  const float* Wk = (const float*)d_in[1];
  const float* Wv = (const float*)d_in[2];
  const float* Wq = (const float*)d_in[3];
  const float* Wout = (const float*)d_in[4];
  const float* w_lr = (const float*)d_in[5];
  const float* b_lr = (const float*)d_in[6];
  const float* w_mom = (const float*)d_in[7];
  const float* b_mom = (const float*)d_in[8];
  const float* w_dec = (const float*)d_in[9];
  const float* b_dec = (const float*)d_in[10];
  const float* w_gate = (const float*)d_in[11];
  const float* b_gate = (const float*)d_in[12];
  const float* Wmem0 = (const float*)d_in[13];
  const float* Wmem1 = (const float*)d_in[14];
  const float* Wmemout = (const float*)d_in[15];
  const float* Wvexp = (const float*)d_in[16];
  float* out = (float*)d_out;
  (void)n_in; (void)in_sizes; (void)out_size;

  const long F = 1048576;
  const long BIG = 2097152;           // 1024*2048
  const long SB2 = 2097152, SB1 = 1048576;
  float* ws = (float*)d_ws;
  if (ws_size < (size_t)25043464 * sizeof(float)) return;

  us* kp_b   = (us*)ws;               // [0,1F) : 2048x1024 bf16 chunk-major
  us* qp_b   = (us*)(ws + F);         // [1,2)
  float* vexp = ws + 2 * F;           // [2,4) : 2048x1024 f32 chunk-major
  float* W0  = ws + 4 * F;            // [4,6) : 1024x2048 f32
  float* W1  = ws + 6 * F;            // [6,8) : 2048x1024 f32
  float* S0  = ws + 8 * F;            // [8,10)
  float* S1  = ws + 10 * F;           // [10,12)
  us* XA     = (us*)(ws + 12 * F);    // [12,14) : [2][1024][2048] bf16 | xb (prologue)
  us* XB     = (us*)(ws + 14 * F);    // [14,16) : same | Wkb/Wqb/Wvb (prologue)
  us* XT     = (us*)(ws + 16 * F);    // [16,18) : [2][2048][1024] | vlin+WvexpT (prologue)
  us* Ab     = (us*)(ws + 18 * F);    // [18,19) : [2][1024][1024] | Woutb (final)
  float* SCR = ws + 19 * F;           // [19,20) : Bb | lin | chunk scratch
  us* W0bT   = (us*)(ws + 20 * F);    // [20,21) : 2048x1024 bf16
  us* W1bT   = (us*)(ws + 21 * F);    // [21,22) : 1024x2048 bf16
  us* W1b    = (us*)(ws + 22 * F);    // [22,23) : 2048x1024 bf16
  us* WmoT   = (us*)(ws + 23 * F);    // [23,23.25) : 512x1024 bf16
  us* retrv  = (us*)(ws + 23 * F + 262144);   // 2048x512 bf16 chunk-major (0.5F)
  float* smal = ws + 23 * F + 262144 + 524288;
  float* og   = smal;
  float* lrv  = og + 2048;
  float* momv = lrv + 2048;
  float* decv = momv + 2048;
  float* cpb  = decv + 2048;          // 32*3
  float* w0inv = cpb + 128;
  float* w1inv = w0inv + 64;
  float* parts = w1inv + 64;          // 512 (2 x 256)
  float* inv01 = parts + 512;         // inv[0], inv[1]

  // prologue aliases
  us* xb   = XA;                       // 2048x2048 bf16
  us* Wkb  = XB;                       // 512x2048
  us* Wqb  = XB + 1048576;
  us* Wvb  = XB + 2097152;
  us* vlin = XT;                       // 2048x512 bf16
  us* WvexpT = XT + 1048576;           // 1024x512 bf16
  us* Woutb = Ab;                      // 2048x512 bf16 (final)
  float* lin = SCR;                    // 2048x512 f32 (prologue)
  us* Bb = (us*)SCR;                   // [2][1024][1024] bf16 (NS loop)
  // per-chunk scratch (within SCR, dead before NS loop)
  us* hab   = (us*)SCR;                // 128x2048 bf16  (131072 floats)
  float* gp = SCR + 131072;            // 64x2048 f32    (131072)
  us* pr    = (us*)(SCR + 262144);     // 128x1024 bf16  (65536)
  float* dh = SCR + 327680;            // 64x2048 f32    (131072)
  us* dhT   = (us*)(SCR + 458752);     // 2048x64 bf16   (65536)
  us* rbwT  = (us*)(SCR + 524288);     // 1024x64 bf16   (32768)

  const float NSa = 3.4445f, NSb = -4.7750f, NSc = 2.0315f;

  // ---- init masters + bf16 weight copies ----
  hipMemcpyAsync(W0, Wmem0, (size_t)BIG * 4, hipMemcpyDeviceToDevice, stream);
  hipMemcpyAsync(W1, Wmem1, (size_t)BIG * 4, hipMemcpyDeviceToDevice, stream);
  hipMemsetAsync(S0, 0, (size_t)BIG * 4, stream);
  hipMemsetAsync(S1, 0, (size_t)BIG * 4, stream);
  hipLaunchKernelGGL(tconv_k, dim3(64, 32), dim3(32, 8), 0, stream, Wmem0, W0bT, 1024, 2048);
  hipLaunchKernelGGL(conv_k, dim3(1024), dim3(256), 0, stream, Wmem1, W1b, (int)BIG);
  hipLaunchKernelGGL(tconv_k, dim3(32, 64), dim3(32, 8), 0, stream, Wmem1, W1bT, 2048, 1024);
  hipLaunchKernelGGL(tconv_k, dim3(16, 32), dim3(32, 8), 0, stream, Wmemout, WmoT, 1024, 512);
  hipLaunchKernelGGL(tconv_k, dim3(32, 16), dim3(32, 8), 0, stream, Wvexp, WvexpT, 512, 1024);
  hipLaunchKernelGGL(conv_k, dim3(2048), dim3(256), 0, stream, x, xb, 2048 * 2048);
  hipLaunchKernelGGL(conv_k, dim3(512), dim3(256), 0, stream, Wk, Wkb, 512 * 2048);
  hipLaunchKernelGGL(conv_k, dim3(512), dim3(256), 0, stream, Wq, Wqb, 512 * 2048);
  hipLaunchKernelGGL(conv_k, dim3(512), dim3(256), 0, stream, Wv, Wvb, 512 * 2048);

  // ---- projections + poly (MFMA) ----
  mg<7>(stream, xb, nullptr, Wkb, lin, nullptr, nullptr, nullptr, nullptr, nullptr, 0,
        2048, 512, 2048, 2048, 2048, 512, 0, 0.f, 0.f, 0, 0, 0, 0, 1);
  hipLaunchKernelGGL(polynorm2_k, dim3(2048), dim3(256), 0, stream, lin, kp_b);
  mg<7>(stream, xb, nullptr, Wqb, lin, nullptr, nullptr, nullptr, nullptr, nullptr, 0,
        2048, 512, 2048, 2048, 2048, 512, 0, 0.f, 0.f, 0, 0, 0, 0, 1);
  hipLaunchKernelGGL(polynorm2_k, dim3(2048), dim3(256), 0, stream, lin, qp_b);
  mg<5>(stream, xb, nullptr, Wvb, vlin, nullptr, nullptr, nullptr, nullptr, nullptr, 0,
        2048, 512, 2048, 2048, 2048, 512, 0, 0.f, 0.f, 0, 0, 0, 0, 1);
  mg<17>(stream, vlin, nullptr, WvexpT, vexp, nullptr, nullptr, nullptr, nullptr, nullptr, 0,
         2048, 1024, 512, 512, 512, 1024, 0, 0.f, 0.f, 0, 0, 0, 0, 1);

  // ---- gates + chunk means ----
  hipLaunchKernelGGL(gates_k, dim3(2048), dim3(256), 0, stream, x,
                     w_lr, b_lr, w_mom, b_mom, w_dec, b_dec, w_gate, b_gate,
                     lrv, momv, decv, og);
  hipLaunchKernelGGL(chunk_means_k, dim3(32), dim3(64), 0, stream, lrv, momv, decv, cpb);

  // ---- sequential chunk scan ----
  for (int c = 0; c < 32; ++c) {
    const us* kp_c = kp_b + (size_t)c * 64 * 1024;
    const us* qp_c = qp_b + (size_t)c * 64 * 1024;
    const float* vexp_c = vexp + (size_t)c * 64 * 1024;
    // G1: [qc;kc]@W0 -> hab (gelu), gp (gelu' for grad rows)
    mg<8, 0, 1>(stream, qp_c, kp_c, W0bT, hab, gp, nullptr, nullptr, nullptr, nullptr, 0,
                128, 2048, 1024, 1024, 1024, 2048, 0, 0.f, 0.f, 0, 0, 0, 0, 1);
    // G2: hab@W1 -> pr (rows<64 pred_retr; rows>=64 resid 2*(pred - vexp))
    mg<9>(stream, hab, nullptr, W1bT, pr, nullptr, vexp_c, nullptr, nullptr, nullptr, 0,
          128, 1024, 2048, 2048, 2048, 1024, 1024, 0.f, 0.f, 0, 0, 0, 0, 1);
    // G3: pred@Wmemout -> retrv (chunk-major)
    mg<5>(stream, pr, nullptr, WmoT, retrv + (size_t)c * 64 * 512, nullptr, nullptr,
          nullptr, nullptr, nullptr, 0,
          64, 512, 1024, 1024, 1024, 512, 0, 0.f, 0.f, 0, 0, 0, 0, 1);
    // G4: r@W1^T * gelu' -> dh (f32)
    mg<13>(stream, pr + 64 * 1024, nullptr, W1b, dh, nullptr, gp, nullptr, nullptr, nullptr, 0,
           64, 2048, 1024, 1024, 1024, 2048, 2048, 0.f, 0.f, 0, 0, 0, 0, 1);
    hipLaunchKernelGGL(sampnorm2_k, dim3(64), dim3(256), 0, stream,
                       kp_b, dh, hab, pr, w0inv, w1inv, c);
    hipLaunchKernelGGL((wtrans_k<1>), dim3(64, 2), dim3(32, 8), 0, stream, dh, w0inv, dhT, 2048, 2048);
    hipLaunchKernelGGL((wtrans_k<0>), dim3(32, 2), dim3(32, 8), 0, stream, pr + 64 * 1024, w1inv,
                       rbwT, 1024, 1024);
    // G5: S0 = mom*S0 - lr*(kc^T dh_w)
    mg<14, 1>(stream, kp_c, nullptr, dhT, S0, nullptr, nullptr, nullptr, nullptr, cpb, c,
              1024, 2048, 64, 1024, 64, 2048, 0, 0.f, 0.f, 0, 0, 0, 0, 1);
    // G6: S1 = mom*S1 - lr*(a^T r_w)
    mg<14, 1>(stream, hab + 64 * 2048, nullptr, rbwT, S1, nullptr, nullptr, nullptr, nullptr, cpb, c,
              2048, 1024, 64, 2048, 64, 1024, 0, 0.f, 0.f, 0, 0, 0, 0, 1);

    // ---- batched NS5: batch0 = S0 (1024x2048), batch1 = S1^T ----
    hipLaunchKernelGGL(frob2_k, dim3(256, 1, 2), dim3(256), 0, stream, S0, S1, (int)BIG, parts);
    hipLaunchKernelGGL(frob_fin2_k, dim3(2), dim3(256), 0, stream, parts, inv01);
    hipLaunchKernelGGL(scale_dual_k, dim3(64, 32), dim3(32, 8), 0, stream,
                       S0, XA, XT, inv01, 1024, 2048);
    hipLaunchKernelGGL(scale_dual_k, dim3(32, 64), dim3(32, 8), 0, stream,
                       S1, XT + SB2, XA + SB2, inv01 + 1, 2048, 1024);

    us* Xc = XA;
    us* Xn = XB;
    for (int it = 0; it < 5; ++it) {
      // Ab = Xc @ Xc^T
      mg<5>(stream, Xc, nullptr, Xc, Ab, nullptr, nullptr, nullptr, nullptr, nullptr, 0,
            1024, 1024, 2048, 2048, 2048, 1024, 0, 0.f, 0.f, SB2, SB2, SB1, 0, 2);
      // Bb = NSc*(Ab@Ab) + NSb*Ab
      mg<6>(stream, Ab, nullptr, Ab, Bb, nullptr, Ab, nullptr, nullptr, nullptr, 0,
            1024, 1024, 1024, 1024, 1024, 1024, 1024, NSc, NSb, SB1, SB1, SB1, SB1, 2);
      // Xn = Bb@Xc + NSa*Xc
      mg<6>(stream, Bb, nullptr, XT, Xn, nullptr, Xc, nullptr, nullptr, nullptr, 0,
            1024, 2048, 1024, 1024, 1024, 2048, 2048, 1.0f, NSa, SB1, SB2, SB2, SB2, 2);
      if (it < 4)
        hipLaunchKernelGGL(tbf_k, dim3(64, 32, 2), dim3(32, 8), 0, stream, Xn, XT);
      us* tmp = Xc; Xc = Xn; Xn = tmp;
    }
    hipLaunchKernelGGL(wupd0_k, dim3(64, 32), dim3(32, 8), 0, stream, W0, Xc, W0bT, cpb, c);
    hipLaunchKernelGGL(wupd1_k, dim3(64, 32), dim3(32, 8), 0, stream, W1, Xc + SB2, W1b, W1bT, cpb, c);
  }

  // ---- final: out = x + (retrv_tok @ Wout^T) * og ----
  hipLaunchKernelGGL(conv_k, dim3(1024), dim3(256), 0, stream, Wout, Woutb, 2048 * 512);
  mg<15, 0, 0, 1>(stream, retrv, nullptr, Woutb, out, nullptr, nullptr, x, og, nullptr, 0,
                  2048, 2048, 512, 512, 512, 2048, 0, 0.f, 0.f, 0, 0, 0, 0, 1);
}